// Round 17
// baseline (149.653 us; speedup 1.0000x reference)
//
#include <hip/hip_runtime.h>
#include <hip/hip_bf16.h>

#define B_ 2
#define T_ 2048
#define C_ 1024
#define H_ 16
#define HD_ 64
#define O_ 1152   // C + 2*HD

#define NX  (B_ * T_ * C_)      // 4194304
#define NW1 (O_ * C_)           // 1179648
#define NW2 (C_ * C_)           // 1048576

// softmax runs in exp2 domain: Q pre-scale = (1/8) * log2(e)
#define QSCALE 0.1803368801111244f

typedef __attribute__((ext_vector_type(8))) short bf16x8;
typedef __attribute__((ext_vector_type(4))) float f32x4;
typedef __attribute__((ext_vector_type(16))) float f32x16;
typedef __attribute__((ext_vector_type(4))) unsigned u32x4;
typedef __attribute__((ext_vector_type(2))) unsigned u32x2;

__device__ inline short f2bf(float f) {
    union { float f; unsigned u; } v; v.f = f;
    unsigned r = v.u + 0x7FFFu + ((v.u >> 16) & 1u);
    return (short)(r >> 16);
}
__device__ inline float bf2f(short s) {
    union { unsigned u; float f; } v; v.u = ((unsigned)(unsigned short)s) << 16;
    return v.f;
}
// native 2^x (v_exp_f32)
__device__ inline float exp2fast(float x) { return __builtin_amdgcn_exp2f(x); }
// packed bf16(lo) | bf16(hi)<<16, RNE
__device__ inline unsigned cvtpk(float lo, float hi) {
    unsigned r;
    asm("v_cvt_pk_bf16_f32 %0, %1, %2" : "=v"(r) : "v"(lo), "v"(hi));
    return r;
}
// permlane32_swap via builtin (hazard-safe: compiler inserts the required
// VALU->permlane wait states; raw inline asm did not - round 10 failure).
__device__ inline u32x2 pswap(unsigned a, unsigned b) {
    return __builtin_amdgcn_permlane32_swap(a, b, false, false);
}
// cross-half (lane^32) max/add, direction-agnostic
__device__ inline float xmax32(float x) {
    u32x2 r = pswap(__float_as_uint(x), __float_as_uint(x));
    return fmaxf(__uint_as_float(r[0]), __uint_as_float(r[1]));
}
__device__ inline float xadd32(float x) {
    u32x2 r = pswap(__float_as_uint(x), __float_as_uint(x));
    return __uint_as_float(r[0]) + __uint_as_float(r[1]);
}

// async global -> LDS, 16 B per lane (wave-uniform LDS base + lane*16)
#define GLL16(gp, lp) __builtin_amdgcn_global_load_lds( \
    (const __attribute__((address_space(1))) unsigned int*)(gp), \
    (__attribute__((address_space(3))) unsigned int*)(lp), 16, 0, 0)

// -------- f32 -> bf16 pre-conversion of x, Wqkv, Wproj (one launch) --------
__global__ __launch_bounds__(256) void cvt_bf16(const float* __restrict__ x,
        const float* __restrict__ w1, const float* __restrict__ w2,
        short* __restrict__ xb, short* __restrict__ w1b, short* __restrict__ w2b) {
    size_t i = ((size_t)blockIdx.x * 256 + threadIdx.x) * 8;
    const float* src; short* dst; size_t off;
    if (i < (size_t)NX)              { src = x;  dst = xb;  off = i; }
    else if (i < (size_t)NX + NW1)   { src = w1; dst = w1b; off = i - NX; }
    else                             { src = w2; dst = w2b; off = i - NX - NW1; }
    f32x4 a = *(const f32x4*)(src + off);
    f32x4 b = *(const f32x4*)(src + off + 4);
    bf16x8 r;
    r[0] = f2bf(a[0]); r[1] = f2bf(a[1]); r[2] = f2bf(a[2]); r[3] = f2bf(a[3]);
    r[4] = f2bf(b[0]); r[5] = f2bf(b[1]); r[6] = f2bf(b[2]); r[7] = f2bf(b[3]);
    *(bf16x8*)(dst + off) = r;
}

// C(M,N) = A(M,K) * B(N,K)^T, bf16 inputs, fp32 accum.
// v9 (round-16, kept): 128x64 block tile, 2.25/2.0 blocks per CU, LDS
// double-buffer with one barrier per k-step (stage(it+1) flies under
// compute(it)); global_load_lds width=16. 4 waves (2x2), wave = 64x32.
template <bool OUT_BF16>
__global__ __launch_bounds__(256) void gemm_bt(const short* __restrict__ A,
                                               const short* __restrict__ Bm,
                                               void* __restrict__ Cv,
                                               int M, int N, int K) {
    __shared__ short lA[2][128 * 32];   // 16 KB
    __shared__ short lB[2][64 * 32];    //  8 KB
    int ntn = N >> 6;
    int nwg = (M >> 7) * ntn;
    int cpx = nwg >> 3;                         // grids are %8 == 0
    int bid = (int)blockIdx.x;
    int swz = (bid % 8) * cpx + bid / 8;        // bijective XCD swizzle
    int m0 = (swz / ntn) << 7;
    int n0 = (swz % ntn) << 6;
    int t = threadIdx.x;
    int wid = t >> 6, l = t & 63;
    int wr = wid >> 1, wc = wid & 1;
    int c = l & 15, g = l >> 4;

    // staging: thread t covers LDS bytes [t*16, t*16+16) = row t/4, k-chunk t%4
    const short* gA0 = A + (size_t)(m0 + (t >> 2)) * K + (t & 3) * 8;
    const short* gA1 = gA0 + (size_t)64 * K;
    const short* gB0 = Bm + (size_t)(n0 + (t >> 2)) * K + (t & 3) * 8;

    int nstep = K >> 5;
    f32x4 acc[4][2] = {};
    int cur = 0;
    GLL16(gA0, &lA[0][t * 8]);
    GLL16(gA1, &lA[0][64 * 32 + t * 8]);
    GLL16(gB0, &lB[0][t * 8]);
    for (int it = 0; it < nstep; it++) {
        __syncthreads();                        // drains stage into lX[cur]
        if (it + 1 < nstep) {                   // stage next, overlapped
            int k = (it + 1) << 5;
            GLL16(gA0 + k, &lA[cur ^ 1][t * 8]);
            GLL16(gA1 + k, &lA[cur ^ 1][64 * 32 + t * 8]);
            GLL16(gB0 + k, &lB[cur ^ 1][t * 8]);
        }
        const short* lap = &lA[cur][(wr * 64 + c) * 32 + g * 8];
        const short* lbp = &lB[cur][(wc * 32 + c) * 32 + g * 8];
        bf16x8 a[4], b[2];
        #pragma unroll
        for (int i = 0; i < 4; i++) a[i] = *(const bf16x8*)(lap + i * 16 * 32);
        #pragma unroll
        for (int j = 0; j < 2; j++) b[j] = *(const bf16x8*)(lbp + j * 16 * 32);
        #pragma unroll
        for (int i = 0; i < 4; i++)
            #pragma unroll
            for (int j = 0; j < 2; j++)
                acc[i][j] = __builtin_amdgcn_mfma_f32_16x16x32_bf16(a[i], b[j], acc[i][j], 0, 0, 0);
        cur ^= 1;
    }

    #pragma unroll
    for (int i = 0; i < 4; i++)
        #pragma unroll
        for (int j = 0; j < 2; j++)
            #pragma unroll
            for (int r = 0; r < 4; r++) {
                int rr = m0 + wr * 64 + i * 16 + g * 4 + r;   // C/D row = (l>>4)*4 + reg
                int cc = n0 + wc * 32 + j * 16 + c;           // C/D col = l&15
                if (OUT_BF16)
                    ((short*)Cv)[(size_t)rr * N + cc] = f2bf(acc[i][j][r]);
                else
                    ((float*)Cv)[(size_t)rr * N + cc] = acc[i][j][r];
            }
}

// Causal depthwise conv1d (K=3) + bias on bf16 qkv; splits -> Q (B,H,T,64,
// scaled QSCALE for exp2-domain softmax), K (B,T,64), V transposed (B,64,T).
__global__ __launch_bounds__(256) void conv_split(const short* __restrict__ qkv,
        const float* __restrict__ qw, const float* __restrict__ qb,
        const float* __restrict__ kw, const float* __restrict__ kbias,
        const float* __restrict__ vw, const float* __restrict__ vbias,
        short* __restrict__ Qs, short* __restrict__ Kb, short* __restrict__ Vt) {
    int idx = blockIdx.x * 256 + threadIdx.x;
    int ch = idx % O_;
    int bt = idx / O_;
    int t = bt % T_;
    int b = bt / T_;
    const short* p = qkv + (size_t)bt * O_ + ch;
    float x2 = bf2f(p[0]);
    float x1 = (t >= 1) ? bf2f(p[-O_]) : 0.f;
    float x0 = (t >= 2) ? bf2f(p[-2 * O_]) : 0.f;
    float w0, w1, w2, bias;
    if (ch < C_)             { w0 = qw[ch*3]; w1 = qw[ch*3+1]; w2 = qw[ch*3+2]; bias = qb[ch]; }
    else if (ch < C_ + HD_)  { int cc = ch - C_;       w0 = kw[cc*3]; w1 = kw[cc*3+1]; w2 = kw[cc*3+2]; bias = kbias[cc]; }
    else                     { int cc = ch - C_ - HD_; w0 = vw[cc*3]; w1 = vw[cc*3+1]; w2 = vw[cc*3+2]; bias = vbias[cc]; }
    float y = fmaf(x0, w0, fmaf(x1, w1, fmaf(x2, w2, bias)));
    if (ch < C_) {
        int h = ch >> 6, d = ch & 63;
        Qs[(((size_t)b * H_ + h) * T_ + t) * HD_ + d] = f2bf(y * QSCALE);
    } else if (ch < C_ + HD_) {
        Kb[((size_t)b * T_ + t) * HD_ + (ch - C_)] = f2bf(y);
    } else {
        Vt[((size_t)b * HD_ + (ch - C_ - HD_)) * T_ + t] = f2bf(y);
    }
}

// Flash-style causal MQA, v11 = T15 2-DEEP TILE PIPELINE: QK(t+1)'s 8 MFMAs
// (inputs already in registers, independent of tile t) are issued BEFORE
// softmax(t), so the MFMA pipe computes next-tile scores while the VALU
// runs this tile's softmax; sv(t+1) is ready when iteration t+1 starts.
// Buffer parity via unroll-2 body (all register indices static).
// Keeps: 4-wave sum-balanced blocks, swapped QK^T, exp2 softmax, tree
// reductions, defer-max (T13), permlane32_swap (T12), K prefetch, V hoist.
// C/D layout (m74-verified): col=lane&31, row=(reg&3)+8*(reg>>2)+4*(lane>>5).
__global__ __launch_bounds__(256) void attn_kernel(const short* __restrict__ Qs,
        const short* __restrict__ Kb, const short* __restrict__ Vt,
        short* __restrict__ Y) {
    int bh = blockIdx.y;
    int b = bh >> 4;
    int h = bh & 15;
    int wid = threadIdx.x >> 6, l = threadIdx.x & 63;
    int ql = l & 31, hi = l >> 5;
    int k2 = blockIdx.x;                       // 0..15
    int qt = (wid < 2) ? (2 * k2 + wid) : (63 - 2 * k2 - (wid & 1));
    int qbase = qt * 32;
    int qi = qbase + ql;

    // Q B-fragments, 4 contraction steps of 16 over HD=64 (col=q=ql, d=hi*8+j)
    const short* Qp = Qs + ((size_t)bh * T_ + qi) * HD_ + hi * 8;
    bf16x8 qf[4];
    #pragma unroll
    for (int s = 0; s < 4; s++) qf[s] = *(const bf16x8*)(Qp + s * 16);

    f32x16 Oa0 = {}, Oa1 = {};                 // O^T, d-blocks [0,32) and [32,64)
    float mrow = -1e30f, lsum = 0.f;

    const short* Kbase = Kb + (size_t)b * T_ * HD_;
    const short* Vbase = Vt + (size_t)b * HD_ * T_;

    auto LDK = [&](int kt, bf16x8 (&dst)[8]) {
        #pragma unroll
        for (int s = 0; s < 4; s++) {
            dst[s]     = *(const bf16x8*)(Kbase + (size_t)(kt + ql) * HD_ + s * 16 + hi * 8);
            dst[4 + s] = *(const bf16x8*)(Kbase + (size_t)(kt + 32 + ql) * HD_ + s * 16 + hi * 8);
        }
    };
    auto QK = [&](bf16x8 (&kk)[8], f32x16& o0, f32x16& o1) {
        #pragma unroll
        for (int s = 0; s < 4; s++)
            o0 = __builtin_amdgcn_mfma_f32_32x32x16_bf16(kk[s], qf[s], o0, 0, 0, 0);
        #pragma unroll
        for (int s = 0; s < 4; s++)
            o1 = __builtin_amdgcn_mfma_f32_32x32x16_bf16(kk[4 + s], qf[s], o1, 0, 0, 0);
    };

    int nt = (qt >> 1) + 1;
    f32x16 sv0 = {}, sv1 = {};                 // scores of tile `it`
    bf16x8 kA[8], kB[8];
    LDK(0, kA);
    QK(kA, sv0, sv1);                          // prologue: scores(0)
    if (nt > 1) LDK(64, kB);                   // K(1) in flight

    // BODY(it): kuse holds K(it+1) (arrived); kload receives K(it+2).
    auto BODY = [&](int it, bf16x8 (&kuse)[8], bf16x8 (&kload)[8]) {
        int kt0 = it * 64;
        // ---- 1) next-tile QK first: MFMA pipe fills while VALU does softmax ----
        f32x16 nx0 = {}, nx1 = {};
        if (it + 1 < nt) {
            QK(kuse, nx0, nx1);
            if (it + 2 < nt) LDK((it + 2) * 64, kload);
        }
        // ---- 2) this tile's V loads (fly under softmax) ----
        bf16x8 vv0[4], vv1[4];                  // u -> koff = u*16
        #pragma unroll
        for (int u = 0; u < 4; u++) {
            int koff = kt0 + u * 16 + hi * 8;
            vv0[u] = *(const bf16x8*)(Vbase + (size_t)ql * T_ + koff);
            vv1[u] = *(const bf16x8*)(Vbase + (size_t)(32 + ql) * T_ + koff);
        }
        // ---- 3) causal mask (diagonal tile only; scale folded into Q) ----
        if (kt0 + 64 > qbase) {
            #pragma unroll
            for (int r = 0; r < 16; r++) {
                int kl = (r & 3) + 8 * (r >> 2) + 4 * hi;
                if (kt0 + kl > qi)      sv0[r] = -1e30f;
                if (kt0 + 32 + kl > qi) sv1[r] = -1e30f;
            }
        }
        // ---- 4) row max: depth-5 tree + cross-half combine ----
        float t8[8];
        #pragma unroll
        for (int r = 0; r < 8; r++)
            t8[r] = fmaxf(fmaxf(sv0[r], sv0[r + 8]), fmaxf(sv1[r], sv1[r + 8]));
        float pmax = fmaxf(fmaxf(fmaxf(t8[0], t8[4]), fmaxf(t8[1], t8[5])),
                           fmaxf(fmaxf(t8[2], t8[6]), fmaxf(t8[3], t8[7])));
        pmax = xmax32(pmax);
        // ---- defer-max (T13): rescale only when max grew past THR=8 ----
        if (!__all(pmax <= mrow + 8.f)) {
            float nm = fmaxf(mrow, pmax);
            float alpha = exp2fast(mrow - nm);
            mrow = nm;
            lsum *= alpha;
            #pragma unroll
            for (int r = 0; r < 16; r++) { Oa0[r] *= alpha; Oa1[r] *= alpha; }
        }
        // ---- 5) P = exp2(S - m); sum via depth-5 tree + cross-half add ----
        #pragma unroll
        for (int r = 0; r < 16; r++) sv0[r] = exp2fast(sv0[r] - mrow);
        #pragma unroll
        for (int r = 0; r < 16; r++) sv1[r] = exp2fast(sv1[r] - mrow);
        float s8[8];
        #pragma unroll
        for (int r = 0; r < 8; r++)
            s8[r] = (sv0[r] + sv0[r + 8]) + (sv1[r] + sv1[r + 8]);
        float psum = ((s8[0] + s8[4]) + (s8[1] + s8[5])) +
                     ((s8[2] + s8[6]) + (s8[3] + s8[7]));
        lsum += xadd32(psum);
        // ---- 6) P redistribution (cvt_pk + permlane32_swap) + PV ----
        #pragma unroll
        for (int sub = 0; sub < 2; sub++) {
            #pragma unroll
            for (int hh = 0; hh < 2; hh++) {
                unsigned X0, X1, X2, X3;
                if (sub == 0) {
                    X0 = cvtpk(sv0[hh * 8 + 0], sv0[hh * 8 + 1]);
                    X1 = cvtpk(sv0[hh * 8 + 2], sv0[hh * 8 + 3]);
                    X2 = cvtpk(sv0[hh * 8 + 4], sv0[hh * 8 + 5]);
                    X3 = cvtpk(sv0[hh * 8 + 6], sv0[hh * 8 + 7]);
                } else {
                    X0 = cvtpk(sv1[hh * 8 + 0], sv1[hh * 8 + 1]);
                    X1 = cvtpk(sv1[hh * 8 + 2], sv1[hh * 8 + 3]);
                    X2 = cvtpk(sv1[hh * 8 + 4], sv1[hh * 8 + 5]);
                    X3 = cvtpk(sv1[hh * 8 + 6], sv1[hh * 8 + 7]);
                }
                u32x2 r02 = pswap(X0, X2);
                u32x2 r13 = pswap(X1, X3);
                union { u32x4 u; bf16x8 v; } pw;
                pw.u[0] = r02[0];   // k elems (hi*8 + 0,1)
                pw.u[1] = r13[0];   // k elems (hi*8 + 2,3)
                pw.u[2] = r02[1];   // k elems (hi*8 + 4,5)
                pw.u[3] = r13[1];   // k elems (hi*8 + 6,7)
                int u = sub * 2 + hh;
                Oa0 = __builtin_amdgcn_mfma_f32_32x32x16_bf16(vv0[u], pw.v, Oa0, 0, 0, 0);
                Oa1 = __builtin_amdgcn_mfma_f32_32x32x16_bf16(vv1[u], pw.v, Oa1, 0, 0, 0);
            }
        }
        // ---- 7) advance pipeline: scores(it+1) become current ----
        sv0 = nx0; sv1 = nx1;
    };

    for (int it = 0; it < nt; it += 2) {
        BODY(it, kB, kA);                      // uses K(it+1)=kB, loads K(it+2)->kA
        if (it + 1 < nt)
            BODY(it + 1, kA, kB);              // uses K(it+2)=kA, loads K(it+3)->kB
    }

    // ---- epilogue: normalize, write one Y-row segment per lane ----
    float inv = 1.f / lsum;
    size_t orow = ((size_t)b * T_ + qi) * C_ + h * HD_;
    #pragma unroll
    for (int r = 0; r < 16; r += 2) {
        int d = (r & 3) + 8 * (r >> 2) + 4 * hi;       // r even -> d even; (r,r+1)->(d,d+1)
        *(unsigned*)(Y + orow + d)      = cvtpk(Oa0[r] * inv, Oa0[r + 1] * inv);
        *(unsigned*)(Y + orow + 32 + d) = cvtpk(Oa1[r] * inv, Oa1[r + 1] * inv);
    }
}

extern "C" void kernel_launch(void* const* d_in, const int* in_sizes, int n_in,
                              void* d_out, int out_size, void* d_ws, size_t ws_size,
                              hipStream_t stream) {
    const float* x     = (const float*)d_in[0];
    const float* Wqkv  = (const float*)d_in[1];
    const float* qw    = (const float*)d_in[2];
    const float* qb    = (const float*)d_in[3];
    const float* kw    = (const float*)d_in[4];
    const float* kbias = (const float*)d_in[5];
    const float* vw    = (const float*)d_in[6];
    const float* vbias = (const float*)d_in[7];
    const float* Wproj = (const float*)d_in[8];

    char* ws = (char*)d_ws;
    short* xb     = (short*)ws;                    //  8388608 B (reused as Ybf later)
    short* Wqkvb  = (short*)(ws + 8388608);        //  2359296 B
    short* Wprojb = (short*)(ws + 10747904);       //  2097152 B
    short* qkvb   = (short*)(ws + 12845056);       //  9437184 B
    short* Qsc    = (short*)(ws + 22282240);       //  8388608 B
    short* Kbf    = (short*)(ws + 30670848);       //   524288 B
    short* Vtr    = (short*)(ws + 31195136);       //   524288 B  (total 31.7 MB)
    short* Ybf    = xb;                            // x dead after gemm1

    const int M = B_ * T_;  // 4096

    // 0) f32 -> bf16: x, Wqkv, Wproj
    cvt_bf16<<<dim3(3136), 256, 0, stream>>>(x, Wqkv, Wproj, xb, Wqkvb, Wprojb);

    // 1) qkv = x @ Wqkv^T  (bf16 out)   grid 32*18 = 576 (%8==0)
    gemm_bt<true><<<dim3((M / 128) * (O_ / 64)), 256, 0, stream>>>(
        xb, Wqkvb, qkvb, M, O_, C_);

    // 2) causal dwconv + split + scale + V-transpose
    conv_split<<<dim3((B_ * T_ * O_) / 256), 256, 0, stream>>>(
        qkvb, qw, qb, kw, kbias, vw, vbias, Qsc, Kbf, Vtr);

    // 3) causal MQA attention -> y (B,T,C) bf16   (T15 2-deep pipeline)
    attn_kernel<<<dim3(16, B_ * H_), 256, 0, stream>>>(Qsc, Kbf, Vtr, Ybf);

    // 4) out = y @ Wproj^T -> f32 d_out   grid 32*16 = 512 (%8==0)
    gemm_bt<false><<<dim3((M / 128) * (C_ / 64)), 256, 0, stream>>>(
        Ybf, Wprojb, (float*)d_out, M, C_, C_);
}

// Round 18
// 137.362 us; speedup vs baseline: 1.0895x; 1.0895x over previous
//
#include <hip/hip_runtime.h>
#include <hip/hip_bf16.h>

#define B_ 2
#define T_ 2048
#define C_ 1024
#define H_ 16
#define HD_ 64
#define O_ 1152   // C + 2*HD

#define NX  (B_ * T_ * C_)      // 4194304
#define NW1 (O_ * C_)           // 1179648
#define NW2 (C_ * C_)           // 1048576

// softmax runs in exp2 domain: Q pre-scale = (1/8) * log2(e)
#define QSCALE 0.1803368801111244f

typedef __attribute__((ext_vector_type(8))) short bf16x8;
typedef __attribute__((ext_vector_type(4))) float f32x4;
typedef __attribute__((ext_vector_type(16))) float f32x16;
typedef __attribute__((ext_vector_type(4))) unsigned u32x4;
typedef __attribute__((ext_vector_type(2))) unsigned u32x2;

__device__ inline short f2bf(float f) {
    union { float f; unsigned u; } v; v.f = f;
    unsigned r = v.u + 0x7FFFu + ((v.u >> 16) & 1u);
    return (short)(r >> 16);
}
__device__ inline float bf2f(short s) {
    union { unsigned u; float f; } v; v.u = ((unsigned)(unsigned short)s) << 16;
    return v.f;
}
// native 2^x (v_exp_f32)
__device__ inline float exp2fast(float x) { return __builtin_amdgcn_exp2f(x); }
// packed bf16(lo) | bf16(hi)<<16, RNE
__device__ inline unsigned cvtpk(float lo, float hi) {
    unsigned r;
    asm("v_cvt_pk_bf16_f32 %0, %1, %2" : "=v"(r) : "v"(lo), "v"(hi));
    return r;
}
// permlane32_swap via builtin (hazard-safe: compiler inserts the required
// VALU->permlane wait states; raw inline asm did not - round 10 failure).
__device__ inline u32x2 pswap(unsigned a, unsigned b) {
    return __builtin_amdgcn_permlane32_swap(a, b, false, false);
}
// cross-half (lane^32) max/add, direction-agnostic
__device__ inline float xmax32(float x) {
    u32x2 r = pswap(__float_as_uint(x), __float_as_uint(x));
    return fmaxf(__uint_as_float(r[0]), __uint_as_float(r[1]));
}
__device__ inline float xadd32(float x) {
    u32x2 r = pswap(__float_as_uint(x), __float_as_uint(x));
    return __uint_as_float(r[0]) + __uint_as_float(r[1]);
}

// async global -> LDS, 16 B per lane (wave-uniform LDS base + lane*16)
#define GLL16(gp, lp) __builtin_amdgcn_global_load_lds( \
    (const __attribute__((address_space(1))) unsigned int*)(gp), \
    (__attribute__((address_space(3))) unsigned int*)(lp), 16, 0, 0)

// -------- f32 -> bf16 pre-conversion of x, Wqkv, Wproj (one launch) --------
__global__ __launch_bounds__(256) void cvt_bf16(const float* __restrict__ x,
        const float* __restrict__ w1, const float* __restrict__ w2,
        short* __restrict__ xb, short* __restrict__ w1b, short* __restrict__ w2b) {
    size_t i = ((size_t)blockIdx.x * 256 + threadIdx.x) * 8;
    const float* src; short* dst; size_t off;
    if (i < (size_t)NX)              { src = x;  dst = xb;  off = i; }
    else if (i < (size_t)NX + NW1)   { src = w1; dst = w1b; off = i - NX; }
    else                             { src = w2; dst = w2b; off = i - NX - NW1; }
    f32x4 a = *(const f32x4*)(src + off);
    f32x4 b = *(const f32x4*)(src + off + 4);
    bf16x8 r;
    r[0] = f2bf(a[0]); r[1] = f2bf(a[1]); r[2] = f2bf(a[2]); r[3] = f2bf(a[3]);
    r[4] = f2bf(b[0]); r[5] = f2bf(b[1]); r[6] = f2bf(b[2]); r[7] = f2bf(b[3]);
    *(bf16x8*)(dst + off) = r;
}

// C(M,N) = A(M,K) * B(N,K)^T, bf16 inputs, fp32 accum.
// v9 (round-16, kept): 128x64 block tile, 2.25/2.0 blocks per CU, LDS
// double-buffer with one barrier per k-step (stage(it+1) flies under
// compute(it)); global_load_lds width=16. 4 waves (2x2), wave = 64x32.
template <bool OUT_BF16>
__global__ __launch_bounds__(256) void gemm_bt(const short* __restrict__ A,
                                               const short* __restrict__ Bm,
                                               void* __restrict__ Cv,
                                               int M, int N, int K) {
    __shared__ short lA[2][128 * 32];   // 16 KB
    __shared__ short lB[2][64 * 32];    //  8 KB
    int ntn = N >> 6;
    int nwg = (M >> 7) * ntn;
    int cpx = nwg >> 3;                         // grids are %8 == 0
    int bid = (int)blockIdx.x;
    int swz = (bid % 8) * cpx + bid / 8;        // bijective XCD swizzle
    int m0 = (swz / ntn) << 7;
    int n0 = (swz % ntn) << 6;
    int t = threadIdx.x;
    int wid = t >> 6, l = t & 63;
    int wr = wid >> 1, wc = wid & 1;
    int c = l & 15, g = l >> 4;

    // staging: thread t covers LDS bytes [t*16, t*16+16) = row t/4, k-chunk t%4
    const short* gA0 = A + (size_t)(m0 + (t >> 2)) * K + (t & 3) * 8;
    const short* gA1 = gA0 + (size_t)64 * K;
    const short* gB0 = Bm + (size_t)(n0 + (t >> 2)) * K + (t & 3) * 8;

    int nstep = K >> 5;
    f32x4 acc[4][2] = {};
    int cur = 0;
    GLL16(gA0, &lA[0][t * 8]);
    GLL16(gA1, &lA[0][64 * 32 + t * 8]);
    GLL16(gB0, &lB[0][t * 8]);
    for (int it = 0; it < nstep; it++) {
        __syncthreads();                        // drains stage into lX[cur]
        if (it + 1 < nstep) {                   // stage next, overlapped
            int k = (it + 1) << 5;
            GLL16(gA0 + k, &lA[cur ^ 1][t * 8]);
            GLL16(gA1 + k, &lA[cur ^ 1][64 * 32 + t * 8]);
            GLL16(gB0 + k, &lB[cur ^ 1][t * 8]);
        }
        const short* lap = &lA[cur][(wr * 64 + c) * 32 + g * 8];
        const short* lbp = &lB[cur][(wc * 32 + c) * 32 + g * 8];
        bf16x8 a[4], b[2];
        #pragma unroll
        for (int i = 0; i < 4; i++) a[i] = *(const bf16x8*)(lap + i * 16 * 32);
        #pragma unroll
        for (int j = 0; j < 2; j++) b[j] = *(const bf16x8*)(lbp + j * 16 * 32);
        #pragma unroll
        for (int i = 0; i < 4; i++)
            #pragma unroll
            for (int j = 0; j < 2; j++)
                acc[i][j] = __builtin_amdgcn_mfma_f32_16x16x32_bf16(a[i], b[j], acc[i][j], 0, 0, 0);
        cur ^= 1;
    }

    #pragma unroll
    for (int i = 0; i < 4; i++)
        #pragma unroll
        for (int j = 0; j < 2; j++)
            #pragma unroll
            for (int r = 0; r < 4; r++) {
                int rr = m0 + wr * 64 + i * 16 + g * 4 + r;   // C/D row = (l>>4)*4 + reg
                int cc = n0 + wc * 32 + j * 16 + c;           // C/D col = l&15
                if (OUT_BF16)
                    ((short*)Cv)[(size_t)rr * N + cc] = f2bf(acc[i][j][r]);
                else
                    ((float*)Cv)[(size_t)rr * N + cc] = acc[i][j][r];
            }
}

// Causal depthwise conv1d (K=3) + bias on bf16 qkv; splits -> Q (B,H,T,64,
// scaled QSCALE for exp2-domain softmax), K (B,T,64), V transposed (B,64,T).
__global__ __launch_bounds__(256) void conv_split(const short* __restrict__ qkv,
        const float* __restrict__ qw, const float* __restrict__ qb,
        const float* __restrict__ kw, const float* __restrict__ kbias,
        const float* __restrict__ vw, const float* __restrict__ vbias,
        short* __restrict__ Qs, short* __restrict__ Kb, short* __restrict__ Vt) {
    int idx = blockIdx.x * 256 + threadIdx.x;
    int ch = idx % O_;
    int bt = idx / O_;
    int t = bt % T_;
    int b = bt / T_;
    const short* p = qkv + (size_t)bt * O_ + ch;
    float x2 = bf2f(p[0]);
    float x1 = (t >= 1) ? bf2f(p[-O_]) : 0.f;
    float x0 = (t >= 2) ? bf2f(p[-2 * O_]) : 0.f;
    float w0, w1, w2, bias;
    if (ch < C_)             { w0 = qw[ch*3]; w1 = qw[ch*3+1]; w2 = qw[ch*3+2]; bias = qb[ch]; }
    else if (ch < C_ + HD_)  { int cc = ch - C_;       w0 = kw[cc*3]; w1 = kw[cc*3+1]; w2 = kw[cc*3+2]; bias = kbias[cc]; }
    else                     { int cc = ch - C_ - HD_; w0 = vw[cc*3]; w1 = vw[cc*3+1]; w2 = vw[cc*3+2]; bias = vbias[cc]; }
    float y = fmaf(x0, w0, fmaf(x1, w1, fmaf(x2, w2, bias)));
    if (ch < C_) {
        int h = ch >> 6, d = ch & 63;
        Qs[(((size_t)b * H_ + h) * T_ + t) * HD_ + d] = f2bf(y * QSCALE);
    } else if (ch < C_ + HD_) {
        Kb[((size_t)b * T_ + t) * HD_ + (ch - C_)] = f2bf(y);
    } else {
        Vt[((size_t)b * HD_ + (ch - C_ - HD_)) * T_ + t] = f2bf(y);
    }
}

// Flash-style causal MQA, v12 = PERFECT PER-WAVE BALANCE: one wave per block;
// each wave processes the qt-PAIR (p, 63-p) sequentially. Total work per wave
// = (p>>1)+1 + ((63-p)>>1)+1 = 33 tile-units, EXACTLY constant for all p.
// Fixes the SIMD imbalance of sum-balanced 4-wave blocks (wid 0/1 always
// light, wid 2/3 always heavy -> SIMD2/3 ran ~64 serial tile-units while
// SIMD0/1 idled; explains the 72us floor across 6 scheduling variants).
// Grid 1024 one-wave blocks, 4/CU, every SIMD = one 33-unit wave.
// Inner tile body identical to round-16 (K prefetch + V hoist + T12/T13).
// C/D layout (m74-verified): col=lane&31, row=(reg&3)+8*(reg>>2)+4*(lane>>5).
__global__ __launch_bounds__(64) void attn_kernel(const short* __restrict__ Qs,
        const short* __restrict__ Kb, const short* __restrict__ Vt,
        short* __restrict__ Y) {
    int bh = blockIdx.y;
    int b = bh >> 4;
    int h = bh & 15;
    int l = threadIdx.x;
    int ql = l & 31, hi = l >> 5;
    int p = (int)blockIdx.x;                   // 0..31

    const short* Kbase = Kb + (size_t)b * T_ * HD_;
    const short* Vbase = Vt + (size_t)b * HD_ * T_;

    auto LDK = [&](int kt, bf16x8 (&dst)[8]) {
        #pragma unroll
        for (int s = 0; s < 4; s++) {
            dst[s]     = *(const bf16x8*)(Kbase + (size_t)(kt + ql) * HD_ + s * 16 + hi * 8);
            dst[4 + s] = *(const bf16x8*)(Kbase + (size_t)(kt + 32 + ql) * HD_ + s * 16 + hi * 8);
        }
    };

    for (int seg = 0; seg < 2; seg++) {
        int qt = seg ? (63 - p) : p;
        int qbase = qt * 32;
        int qi = qbase + ql;

        // Q B-fragments (col=q=ql, d=hi*8+j)
        const short* Qp = Qs + ((size_t)bh * T_ + qi) * HD_ + hi * 8;
        bf16x8 qf[4];
        #pragma unroll
        for (int s = 0; s < 4; s++) qf[s] = *(const bf16x8*)(Qp + s * 16);

        f32x16 Oa0 = {}, Oa1 = {};             // O^T, d-blocks [0,32) and [32,64)
        float mrow = -1e30f, lsum = 0.f;

        int nt = (qt >> 1) + 1;
        bf16x8 ka[8], kb2[8];
        LDK(0, ka);
        for (int it = 0; it < nt; it++) {
            int kt0 = it * 64;
            // ---- S^T from prefetched K ----
            f32x16 sv0 = {}, sv1 = {};
            #pragma unroll
            for (int s = 0; s < 4; s++)
                sv0 = __builtin_amdgcn_mfma_f32_32x32x16_bf16(ka[s], qf[s], sv0, 0, 0, 0);
            #pragma unroll
            for (int s = 0; s < 4; s++)
                sv1 = __builtin_amdgcn_mfma_f32_32x32x16_bf16(ka[4 + s], qf[s], sv1, 0, 0, 0);
            // ---- issue next tile's K loads + this tile's V loads ----
            int itn = (it + 1 < nt) ? (it + 1) : it;
            LDK(itn * 64, kb2);
            bf16x8 vv0[4], vv1[4];              // u -> koff = u*16
            #pragma unroll
            for (int u = 0; u < 4; u++) {
                int koff = kt0 + u * 16 + hi * 8;
                vv0[u] = *(const bf16x8*)(Vbase + (size_t)ql * T_ + koff);
                vv1[u] = *(const bf16x8*)(Vbase + (size_t)(32 + ql) * T_ + koff);
            }
            // ---- causal mask (diagonal tile only; scale folded into Q) ----
            if (kt0 + 64 > qbase) {
                #pragma unroll
                for (int r = 0; r < 16; r++) {
                    int kl = (r & 3) + 8 * (r >> 2) + 4 * hi;
                    if (kt0 + kl > qi)      sv0[r] = -1e30f;
                    if (kt0 + 32 + kl > qi) sv1[r] = -1e30f;
                }
            }
            // ---- row max: depth-5 tree + cross-half combine ----
            float t8[8];
            #pragma unroll
            for (int r = 0; r < 8; r++)
                t8[r] = fmaxf(fmaxf(sv0[r], sv0[r + 8]), fmaxf(sv1[r], sv1[r + 8]));
            float pmax = fmaxf(fmaxf(fmaxf(t8[0], t8[4]), fmaxf(t8[1], t8[5])),
                               fmaxf(fmaxf(t8[2], t8[6]), fmaxf(t8[3], t8[7])));
            pmax = xmax32(pmax);
            // ---- defer-max (T13): rescale only when max grew past THR=8 ----
            if (!__all(pmax <= mrow + 8.f)) {
                float nm = fmaxf(mrow, pmax);
                float alpha = exp2fast(mrow - nm);
                mrow = nm;
                lsum *= alpha;
                #pragma unroll
                for (int r = 0; r < 16; r++) { Oa0[r] *= alpha; Oa1[r] *= alpha; }
            }
            // ---- P = exp2(S - m); sum via depth-5 tree + cross-half add ----
            #pragma unroll
            for (int r = 0; r < 16; r++) sv0[r] = exp2fast(sv0[r] - mrow);
            #pragma unroll
            for (int r = 0; r < 16; r++) sv1[r] = exp2fast(sv1[r] - mrow);
            float s8[8];
            #pragma unroll
            for (int r = 0; r < 8; r++)
                s8[r] = (sv0[r] + sv0[r + 8]) + (sv1[r] + sv1[r + 8]);
            float psum = ((s8[0] + s8[4]) + (s8[1] + s8[5])) +
                         ((s8[2] + s8[6]) + (s8[3] + s8[7]));
            lsum += xadd32(psum);
            // ---- P redistribution (cvt_pk + permlane32_swap) + PV ----
            #pragma unroll
            for (int sub = 0; sub < 2; sub++) {
                #pragma unroll
                for (int hh = 0; hh < 2; hh++) {
                    unsigned X0, X1, X2, X3;
                    if (sub == 0) {
                        X0 = cvtpk(sv0[hh * 8 + 0], sv0[hh * 8 + 1]);
                        X1 = cvtpk(sv0[hh * 8 + 2], sv0[hh * 8 + 3]);
                        X2 = cvtpk(sv0[hh * 8 + 4], sv0[hh * 8 + 5]);
                        X3 = cvtpk(sv0[hh * 8 + 6], sv0[hh * 8 + 7]);
                    } else {
                        X0 = cvtpk(sv1[hh * 8 + 0], sv1[hh * 8 + 1]);
                        X1 = cvtpk(sv1[hh * 8 + 2], sv1[hh * 8 + 3]);
                        X2 = cvtpk(sv1[hh * 8 + 4], sv1[hh * 8 + 5]);
                        X3 = cvtpk(sv1[hh * 8 + 6], sv1[hh * 8 + 7]);
                    }
                    u32x2 r02 = pswap(X0, X2);
                    u32x2 r13 = pswap(X1, X3);
                    union { u32x4 u; bf16x8 v; } pw;
                    pw.u[0] = r02[0];   // k elems (hi*8 + 0,1)
                    pw.u[1] = r13[0];   // k elems (hi*8 + 2,3)
                    pw.u[2] = r02[1];   // k elems (hi*8 + 4,5)
                    pw.u[3] = r13[1];   // k elems (hi*8 + 6,7)
                    int u = sub * 2 + hh;
                    Oa0 = __builtin_amdgcn_mfma_f32_32x32x16_bf16(vv0[u], pw.v, Oa0, 0, 0, 0);
                    Oa1 = __builtin_amdgcn_mfma_f32_32x32x16_bf16(vv1[u], pw.v, Oa1, 0, 0, 0);
                }
            }
            // ---- rotate prefetch buffer ----
            #pragma unroll
            for (int s = 0; s < 8; s++) ka[s] = kb2[s];
        }
        // ---- epilogue: normalize, write one Y-row segment per lane ----
        float inv = 1.f / lsum;
        size_t orow = ((size_t)b * T_ + qi) * C_ + h * HD_;
        #pragma unroll
        for (int r = 0; r < 16; r += 2) {
            int d = (r & 3) + 8 * (r >> 2) + 4 * hi;   // (r,r+1)->(d,d+1)
            *(unsigned*)(Y + orow + d)      = cvtpk(Oa0[r] * inv, Oa0[r + 1] * inv);
            *(unsigned*)(Y + orow + 32 + d) = cvtpk(Oa1[r] * inv, Oa1[r + 1] * inv);
        }
    }
}

extern "C" void kernel_launch(void* const* d_in, const int* in_sizes, int n_in,
                              void* d_out, int out_size, void* d_ws, size_t ws_size,
                              hipStream_t stream) {
    const float* x     = (const float*)d_in[0];
    const float* Wqkv  = (const float*)d_in[1];
    const float* qw    = (const float*)d_in[2];
    const float* qb    = (const float*)d_in[3];
    const float* kw    = (const float*)d_in[4];
    const float* kbias = (const float*)d_in[5];
    const float* vw    = (const float*)d_in[6];
    const float* vbias = (const float*)d_in[7];
    const float* Wproj = (const float*)d_in[8];

    char* ws = (char*)d_ws;
    short* xb     = (short*)ws;                    //  8388608 B (reused as Ybf later)
    short* Wqkvb  = (short*)(ws + 8388608);        //  2359296 B
    short* Wprojb = (short*)(ws + 10747904);       //  2097152 B
    short* qkvb   = (short*)(ws + 12845056);       //  9437184 B
    short* Qsc    = (short*)(ws + 22282240);       //  8388608 B
    short* Kbf    = (short*)(ws + 30670848);       //   524288 B
    short* Vtr    = (short*)(ws + 31195136);       //   524288 B  (total 31.7 MB)
    short* Ybf    = xb;                            // x dead after gemm1

    const int M = B_ * T_;  // 4096

    // 0) f32 -> bf16: x, Wqkv, Wproj
    cvt_bf16<<<dim3(3136), 256, 0, stream>>>(x, Wqkv, Wproj, xb, Wqkvb, Wprojb);

    // 1) qkv = x @ Wqkv^T  (bf16 out)   grid 32*18 = 576 (%8==0)
    gemm_bt<true><<<dim3((M / 128) * (O_ / 64)), 256, 0, stream>>>(
        xb, Wqkvb, qkvb, M, O_, C_);

    // 2) causal dwconv + split + scale + V-transpose
    conv_split<<<dim3((B_ * T_ * O_) / 256), 256, 0, stream>>>(
        qkvb, qw, qb, kw, kbias, vw, vbias, Qsc, Kbf, Vtr);

    // 3) causal MQA attention -> y (B,T,C) bf16   (balanced qt-pair waves)
    attn_kernel<<<dim3(32, B_ * H_), 64, 0, stream>>>(Qsc, Kbf, Vtr, Ybf);

    // 4) out = y @ Wproj^T -> f32 d_out   grid 32*16 = 512 (%8==0)
    gemm_bt<false><<<dim3((M / 128) * (C_ / 64)), 256, 0, stream>>>(
        Ybf, Wprojb, (float*)d_out, M, C_, C_);
}

// Round 19
// 113.978 us; speedup vs baseline: 1.3130x; 1.2052x over previous
//
#include <hip/hip_runtime.h>
#include <hip/hip_bf16.h>

#define B_ 2
#define T_ 2048
#define C_ 1024
#define H_ 16
#define HD_ 64
#define O_ 1152   // C + 2*HD

#define NX  (B_ * T_ * C_)      // 4194304
#define NW1 (O_ * C_)           // 1179648
#define NW2 (C_ * C_)           // 1048576

// softmax runs in exp2 domain: Q pre-scale = (1/8) * log2(e)
#define QSCALE 0.1803368801111244f

typedef __attribute__((ext_vector_type(8))) short bf16x8;
typedef __attribute__((ext_vector_type(4))) float f32x4;
typedef __attribute__((ext_vector_type(16))) float f32x16;
typedef __attribute__((ext_vector_type(4))) unsigned u32x4;
typedef __attribute__((ext_vector_type(2))) unsigned u32x2;

__device__ inline short f2bf(float f) {
    union { float f; unsigned u; } v; v.f = f;
    unsigned r = v.u + 0x7FFFu + ((v.u >> 16) & 1u);
    return (short)(r >> 16);
}
__device__ inline float bf2f(short s) {
    union { unsigned u; float f; } v; v.u = ((unsigned)(unsigned short)s) << 16;
    return v.f;
}
// native 2^x (v_exp_f32)
__device__ inline float exp2fast(float x) { return __builtin_amdgcn_exp2f(x); }
// packed bf16(lo) | bf16(hi)<<16, RNE
__device__ inline unsigned cvtpk(float lo, float hi) {
    unsigned r;
    asm("v_cvt_pk_bf16_f32 %0, %1, %2" : "=v"(r) : "v"(lo), "v"(hi));
    return r;
}
// permlane32_swap via builtin (hazard-safe: compiler inserts the required
// VALU->permlane wait states; raw inline asm did not - round 10 failure).
__device__ inline u32x2 pswap(unsigned a, unsigned b) {
    return __builtin_amdgcn_permlane32_swap(a, b, false, false);
}
// cross-half (lane^32) max/add, direction-agnostic
__device__ inline float xmax32(float x) {
    u32x2 r = pswap(__float_as_uint(x), __float_as_uint(x));
    return fmaxf(__uint_as_float(r[0]), __uint_as_float(r[1]));
}
__device__ inline float xadd32(float x) {
    u32x2 r = pswap(__float_as_uint(x), __float_as_uint(x));
    return __uint_as_float(r[0]) + __uint_as_float(r[1]);
}

// async global -> LDS, 16 B per lane (wave-uniform LDS base + lane*16)
#define GLL16(gp, lp) __builtin_amdgcn_global_load_lds( \
    (const __attribute__((address_space(1))) unsigned int*)(gp), \
    (__attribute__((address_space(3))) unsigned int*)(lp), 16, 0, 0)

// -------- f32 -> bf16 pre-conversion of x, Wqkv, Wproj (one launch) --------
__global__ __launch_bounds__(256) void cvt_bf16(const float* __restrict__ x,
        const float* __restrict__ w1, const float* __restrict__ w2,
        short* __restrict__ xb, short* __restrict__ w1b, short* __restrict__ w2b) {
    size_t i = ((size_t)blockIdx.x * 256 + threadIdx.x) * 8;
    const float* src; short* dst; size_t off;
    if (i < (size_t)NX)              { src = x;  dst = xb;  off = i; }
    else if (i < (size_t)NX + NW1)   { src = w1; dst = w1b; off = i - NX; }
    else                             { src = w2; dst = w2b; off = i - NX - NW1; }
    f32x4 a = *(const f32x4*)(src + off);
    f32x4 b = *(const f32x4*)(src + off + 4);
    bf16x8 r;
    r[0] = f2bf(a[0]); r[1] = f2bf(a[1]); r[2] = f2bf(a[2]); r[3] = f2bf(a[3]);
    r[4] = f2bf(b[0]); r[5] = f2bf(b[1]); r[6] = f2bf(b[2]); r[7] = f2bf(b[3]);
    *(bf16x8*)(dst + off) = r;
}

// C(M,N) = A(M,K) * B(N,K)^T, bf16 inputs, fp32 accum.
// v9 (round-16, kept): 128x64 block tile, LDS double-buffer, one barrier per
// k-step; global_load_lds width=16. 4 waves (2x2), wave = 64x32.
template <bool OUT_BF16>
__global__ __launch_bounds__(256) void gemm_bt(const short* __restrict__ A,
                                               const short* __restrict__ Bm,
                                               void* __restrict__ Cv,
                                               int M, int N, int K) {
    __shared__ short lA[2][128 * 32];   // 16 KB
    __shared__ short lB[2][64 * 32];    //  8 KB
    int ntn = N >> 6;
    int nwg = (M >> 7) * ntn;
    int cpx = nwg >> 3;                         // grids are %8 == 0
    int bid = (int)blockIdx.x;
    int swz = (bid % 8) * cpx + bid / 8;        // bijective XCD swizzle
    int m0 = (swz / ntn) << 7;
    int n0 = (swz % ntn) << 6;
    int t = threadIdx.x;
    int wid = t >> 6, l = t & 63;
    int wr = wid >> 1, wc = wid & 1;
    int c = l & 15, g = l >> 4;

    const short* gA0 = A + (size_t)(m0 + (t >> 2)) * K + (t & 3) * 8;
    const short* gA1 = gA0 + (size_t)64 * K;
    const short* gB0 = Bm + (size_t)(n0 + (t >> 2)) * K + (t & 3) * 8;

    int nstep = K >> 5;
    f32x4 acc[4][2] = {};
    int cur = 0;
    GLL16(gA0, &lA[0][t * 8]);
    GLL16(gA1, &lA[0][64 * 32 + t * 8]);
    GLL16(gB0, &lB[0][t * 8]);
    for (int it = 0; it < nstep; it++) {
        __syncthreads();                        // drains stage into lX[cur]
        if (it + 1 < nstep) {                   // stage next, overlapped
            int k = (it + 1) << 5;
            GLL16(gA0 + k, &lA[cur ^ 1][t * 8]);
            GLL16(gA1 + k, &lA[cur ^ 1][64 * 32 + t * 8]);
            GLL16(gB0 + k, &lB[cur ^ 1][t * 8]);
        }
        const short* lap = &lA[cur][(wr * 64 + c) * 32 + g * 8];
        const short* lbp = &lB[cur][(wc * 32 + c) * 32 + g * 8];
        bf16x8 a[4], b[2];
        #pragma unroll
        for (int i = 0; i < 4; i++) a[i] = *(const bf16x8*)(lap + i * 16 * 32);
        #pragma unroll
        for (int j = 0; j < 2; j++) b[j] = *(const bf16x8*)(lbp + j * 16 * 32);
        #pragma unroll
        for (int i = 0; i < 4; i++)
            #pragma unroll
            for (int j = 0; j < 2; j++)
                acc[i][j] = __builtin_amdgcn_mfma_f32_16x16x32_bf16(a[i], b[j], acc[i][j], 0, 0, 0);
        cur ^= 1;
    }

    #pragma unroll
    for (int i = 0; i < 4; i++)
        #pragma unroll
        for (int j = 0; j < 2; j++)
            #pragma unroll
            for (int r = 0; r < 4; r++) {
                int rr = m0 + wr * 64 + i * 16 + g * 4 + r;   // C/D row = (l>>4)*4 + reg
                int cc = n0 + wc * 32 + j * 16 + c;           // C/D col = l&15
                if (OUT_BF16)
                    ((short*)Cv)[(size_t)rr * N + cc] = f2bf(acc[i][j][r]);
                else
                    ((float*)Cv)[(size_t)rr * N + cc] = acc[i][j][r];
            }
}

// Causal depthwise conv1d (K=3) + bias on bf16 qkv; splits -> Q (B,H,T,64,
// scaled QSCALE for exp2-domain softmax), K (B,T,64), V transposed (B,64,T).
__global__ __launch_bounds__(256) void conv_split(const short* __restrict__ qkv,
        const float* __restrict__ qw, const float* __restrict__ qb,
        const float* __restrict__ kw, const float* __restrict__ kbias,
        const float* __restrict__ vw, const float* __restrict__ vbias,
        short* __restrict__ Qs, short* __restrict__ Kb, short* __restrict__ Vt) {
    int idx = blockIdx.x * 256 + threadIdx.x;
    int ch = idx % O_;
    int bt = idx / O_;
    int t = bt % T_;
    int b = bt / T_;
    const short* p = qkv + (size_t)bt * O_ + ch;
    float x2 = bf2f(p[0]);
    float x1 = (t >= 1) ? bf2f(p[-O_]) : 0.f;
    float x0 = (t >= 2) ? bf2f(p[-2 * O_]) : 0.f;
    float w0, w1, w2, bias;
    if (ch < C_)             { w0 = qw[ch*3]; w1 = qw[ch*3+1]; w2 = qw[ch*3+2]; bias = qb[ch]; }
    else if (ch < C_ + HD_)  { int cc = ch - C_;       w0 = kw[cc*3]; w1 = kw[cc*3+1]; w2 = kw[cc*3+2]; bias = kbias[cc]; }
    else                     { int cc = ch - C_ - HD_; w0 = vw[cc*3]; w1 = vw[cc*3+1]; w2 = vw[cc*3+2]; bias = vbias[cc]; }
    float y = fmaf(x0, w0, fmaf(x1, w1, fmaf(x2, w2, bias)));
    if (ch < C_) {
        int h = ch >> 6, d = ch & 63;
        Qs[(((size_t)b * H_ + h) * T_ + t) * HD_ + d] = f2bf(y * QSCALE);
    } else if (ch < C_ + HD_) {
        Kb[((size_t)b * T_ + t) * HD_ + (ch - C_)] = f2bf(y);
    } else {
        Vt[((size_t)b * HD_ + (ch - C_ - HD_)) * T_ + t] = f2bf(y);
    }
}

// Flash-style causal MQA, v13 = LDS-SHARED K/V (the L2-overfetch fix).
// Old: every wave loaded K/V with 128B-stride per-lane gathers -> each 16B
// used of a 128B line -> ~2.2 GB L1<-L2 traffic = ~63us floor (matches the
// 72us invariant across 8 scheduling variants). New: block = 4 waves = 4
// HEADS of one (b, qt) sharing ONE coalesced K/V LDS staging (MQA: K/V
// identical across heads): 8x less line traffic x4 sharing = ~135 MB total.
// LDS reads XOR-swizzled (T2/m201: linear GLL dest + pre-swizzled global
// source + swizzled ds_read). CU-pairing: blocks 0..255 = heavy qts,
// 256..511 = complementary light qts (co-resident pairs sum to 65 tiles).
// C/D layout (m74-verified): col=lane&31, row=(reg&3)+8*(reg>>2)+4*(lane>>5).
__global__ __launch_bounds__(256, 2) void attn_kernel(const short* __restrict__ Qs,
        const short* __restrict__ Kb, const short* __restrict__ Vt,
        short* __restrict__ Y) {
    __shared__ short KL[2][64 * 64];   // 16 KB (2 bufs x 8 KB)
    __shared__ short VL[2][64 * 64];   // 16 KB
    int n = (int)blockIdx.x;                   // 0..511
    int half = n >> 8;
    int n2 = n & 255;
    int y = n2 >> 5;                           // 0..7: b*4 + hq
    int qx = n2 & 31;
    int qt = half ? qx : 63 - qx;              // heavy first
    int b = y >> 2;
    int hq = y & 3;
    int t = threadIdx.x;
    int wid = t >> 6, l = t & 63;
    int ql = l & 31, hi = l >> 5;
    int h = hq * 4 + wid;
    int bh = b * H_ + h;
    int qbase = qt * 32;
    int qi = qbase + ql;

    // Q B-fragments (col=q=ql, d=hi*8+j), per-wave head
    const short* Qp = Qs + ((size_t)bh * T_ + qi) * HD_ + hi * 8;
    bf16x8 qf[4];
    #pragma unroll
    for (int s = 0; s < 4; s++) qf[s] = *(const bf16x8*)(Qp + s * 16);

    f32x16 Oa0 = {}, Oa1 = {};                 // O^T, d-blocks [0,32) and [32,64)
    float mrow = -1e30f, lsum = 0.f;

    const short* Kbase = Kb + (size_t)b * T_ * HD_;
    const short* Vbase = Vt + (size_t)b * HD_ * T_;

    // ---- staging geometry: thread t -> row krow = t>>3, col16 = t&7 ----
    // LDS linear slot (row, s16) holds global col16 = s16 ^ (row&7)  (m201).
    int krow = t >> 3;
    int sc = ((t & 7) ^ (krow & 7)) * 8;       // pre-swizzled source col (elems)
    const short* KgA = Kbase + (size_t)krow * HD_ + sc;   // + kt0*64 at stage
    const short* VgA = Vbase + (size_t)krow * T_ + sc;    // + kt0 at stage
    int t8 = t * 8;                             // LDS short index (t*16 bytes)

    auto STAGE = [&](int buf, int kt0) {
        GLL16(KgA + (size_t)kt0 * HD_, &KL[buf][t8]);
        GLL16(KgA + (size_t)kt0 * HD_ + 32 * HD_, &KL[buf][2048 + t8]);
        GLL16(VgA + kt0, &VL[buf][t8]);
        GLL16(VgA + kt0 + (size_t)32 * T_, &VL[buf][2048 + t8]);
    };

    int nt = (qt >> 1) + 1;
    int cur = 0;
    STAGE(0, 0);
    for (int it = 0; it < nt; it++) {
        int kt0 = it * 64;
        __syncthreads();                        // buf[cur] ready (vmcnt drained)
        if (it + 1 < nt) STAGE(cur ^ 1, (it + 1) * 64);
        // ---- S^T from swizzled LDS K ----
        f32x16 sv0 = {}, sv1 = {};
        #pragma unroll
        for (int s = 0; s < 4; s++) {
            bf16x8 ka = *(const bf16x8*)&KL[cur][ql * 64 + (((s * 2 + hi) ^ (ql & 7)) * 8)];
            sv0 = __builtin_amdgcn_mfma_f32_32x32x16_bf16(ka, qf[s], sv0, 0, 0, 0);
        }
        #pragma unroll
        for (int s = 0; s < 4; s++) {
            bf16x8 ka = *(const bf16x8*)&KL[cur][(32 + ql) * 64 + (((s * 2 + hi) ^ (ql & 7)) * 8)];
            sv1 = __builtin_amdgcn_mfma_f32_32x32x16_bf16(ka, qf[s], sv1, 0, 0, 0);
        }
        // ---- causal mask (diagonal tile only; scale folded into Q) ----
        if (kt0 + 64 > qbase) {
            #pragma unroll
            for (int r = 0; r < 16; r++) {
                int kl = (r & 3) + 8 * (r >> 2) + 4 * hi;
                if (kt0 + kl > qi)      sv0[r] = -1e30f;
                if (kt0 + 32 + kl > qi) sv1[r] = -1e30f;
            }
        }
        // ---- row max: depth-5 tree + cross-half combine ----
        float t8v[8];
        #pragma unroll
        for (int r = 0; r < 8; r++)
            t8v[r] = fmaxf(fmaxf(sv0[r], sv0[r + 8]), fmaxf(sv1[r], sv1[r + 8]));
        float pmax = fmaxf(fmaxf(fmaxf(t8v[0], t8v[4]), fmaxf(t8v[1], t8v[5])),
                           fmaxf(fmaxf(t8v[2], t8v[6]), fmaxf(t8v[3], t8v[7])));
        pmax = xmax32(pmax);
        // ---- defer-max (T13): rescale only when max grew past THR=8 ----
        if (!__all(pmax <= mrow + 8.f)) {
            float nm = fmaxf(mrow, pmax);
            float alpha = exp2fast(mrow - nm);
            mrow = nm;
            lsum *= alpha;
            #pragma unroll
            for (int r = 0; r < 16; r++) { Oa0[r] *= alpha; Oa1[r] *= alpha; }
        }
        // ---- P = exp2(S - m); sum via depth-5 tree + cross-half add ----
        #pragma unroll
        for (int r = 0; r < 16; r++) sv0[r] = exp2fast(sv0[r] - mrow);
        #pragma unroll
        for (int r = 0; r < 16; r++) sv1[r] = exp2fast(sv1[r] - mrow);
        float s8[8];
        #pragma unroll
        for (int r = 0; r < 8; r++)
            s8[r] = (sv0[r] + sv0[r + 8]) + (sv1[r] + sv1[r + 8]);
        float psum = ((s8[0] + s8[4]) + (s8[1] + s8[5])) +
                     ((s8[2] + s8[6]) + (s8[3] + s8[7]));
        lsum += xadd32(psum);
        // ---- P redistribution (cvt_pk + permlane32_swap) + PV from LDS V ----
        #pragma unroll
        for (int sub = 0; sub < 2; sub++) {
            #pragma unroll
            for (int hh = 0; hh < 2; hh++) {
                unsigned X0, X1, X2, X3;
                if (sub == 0) {
                    X0 = cvtpk(sv0[hh * 8 + 0], sv0[hh * 8 + 1]);
                    X1 = cvtpk(sv0[hh * 8 + 2], sv0[hh * 8 + 3]);
                    X2 = cvtpk(sv0[hh * 8 + 4], sv0[hh * 8 + 5]);
                    X3 = cvtpk(sv0[hh * 8 + 6], sv0[hh * 8 + 7]);
                } else {
                    X0 = cvtpk(sv1[hh * 8 + 0], sv1[hh * 8 + 1]);
                    X1 = cvtpk(sv1[hh * 8 + 2], sv1[hh * 8 + 3]);
                    X2 = cvtpk(sv1[hh * 8 + 4], sv1[hh * 8 + 5]);
                    X3 = cvtpk(sv1[hh * 8 + 6], sv1[hh * 8 + 7]);
                }
                u32x2 r02 = pswap(X0, X2);
                u32x2 r13 = pswap(X1, X3);
                union { u32x4 u; bf16x8 v; } pw;
                pw.u[0] = r02[0];   // k elems (hi*8 + 0,1)
                pw.u[1] = r13[0];   // k elems (hi*8 + 2,3)
                pw.u[2] = r02[1];   // k elems (hi*8 + 4,5)
                pw.u[3] = r13[1];   // k elems (hi*8 + 6,7)
                int u = sub * 2 + hh;           // V col16 = u*2 + hi
                bf16x8 va0 = *(const bf16x8*)&VL[cur][ql * 64 + (((u * 2 + hi) ^ (ql & 7)) * 8)];
                bf16x8 va1 = *(const bf16x8*)&VL[cur][(32 + ql) * 64 + (((u * 2 + hi) ^ (ql & 7)) * 8)];
                Oa0 = __builtin_amdgcn_mfma_f32_32x32x16_bf16(va0, pw.v, Oa0, 0, 0, 0);
                Oa1 = __builtin_amdgcn_mfma_f32_32x32x16_bf16(va1, pw.v, Oa1, 0, 0, 0);
            }
        }
        cur ^= 1;
    }
    // ---- epilogue: normalize, write one Y-row segment per lane ----
    float inv = 1.f / lsum;
    size_t orow = ((size_t)b * T_ + qi) * C_ + h * HD_;
    #pragma unroll
    for (int r = 0; r < 16; r += 2) {
        int d = (r & 3) + 8 * (r >> 2) + 4 * hi;       // (r,r+1)->(d,d+1)
        *(unsigned*)(Y + orow + d)      = cvtpk(Oa0[r] * inv, Oa0[r + 1] * inv);
        *(unsigned*)(Y + orow + 32 + d) = cvtpk(Oa1[r] * inv, Oa1[r + 1] * inv);
    }
}

extern "C" void kernel_launch(void* const* d_in, const int* in_sizes, int n_in,
                              void* d_out, int out_size, void* d_ws, size_t ws_size,
                              hipStream_t stream) {
    const float* x     = (const float*)d_in[0];
    const float* Wqkv  = (const float*)d_in[1];
    const float* qw    = (const float*)d_in[2];
    const float* qb    = (const float*)d_in[3];
    const float* kw    = (const float*)d_in[4];
    const float* kbias = (const float*)d_in[5];
    const float* vw    = (const float*)d_in[6];
    const float* vbias = (const float*)d_in[7];
    const float* Wproj = (const float*)d_in[8];

    char* ws = (char*)d_ws;
    short* xb     = (short*)ws;                    //  8388608 B (reused as Ybf later)
    short* Wqkvb  = (short*)(ws + 8388608);        //  2359296 B
    short* Wprojb = (short*)(ws + 10747904);       //  2097152 B
    short* qkvb   = (short*)(ws + 12845056);       //  9437184 B
    short* Qsc    = (short*)(ws + 22282240);       //  8388608 B
    short* Kbf    = (short*)(ws + 30670848);       //   524288 B
    short* Vtr    = (short*)(ws + 31195136);       //   524288 B  (total 31.7 MB)
    short* Ybf    = xb;                            // x dead after gemm1

    const int M = B_ * T_;  // 4096

    // 0) f32 -> bf16: x, Wqkv, Wproj
    cvt_bf16<<<dim3(3136), 256, 0, stream>>>(x, Wqkv, Wproj, xb, Wqkvb, Wprojb);

    // 1) qkv = x @ Wqkv^T  (bf16 out)   grid 32*18 = 576 (%8==0)
    gemm_bt<true><<<dim3((M / 128) * (O_ / 64)), 256, 0, stream>>>(
        xb, Wqkvb, qkvb, M, O_, C_);

    // 2) causal dwconv + split + scale + V-transpose
    conv_split<<<dim3((B_ * T_ * O_) / 256), 256, 0, stream>>>(
        qkvb, qw, qb, kw, kbias, vw, vbias, Qsc, Kbf, Vtr);

    // 3) causal MQA attention -> y (B,T,C) bf16   (LDS-shared K/V, 4 heads/block)
    attn_kernel<<<dim3(512), 256, 0, stream>>>(Qsc, Kbf, Vtr, Ybf);

    // 4) out = y @ Wproj^T -> f32 d_out   grid 32*16 = 512 (%8==0)
    gemm_bt<false><<<dim3((M / 128) * (C_ / 64)), 256, 0, stream>>>(
        Ybf, Wprojb, (float*)d_out, M, C_, C_);
}

// Round 20
// 108.657 us; speedup vs baseline: 1.3773x; 1.0490x over previous
//
#include <hip/hip_runtime.h>
#include <hip/hip_bf16.h>

#define B_ 2
#define T_ 2048
#define C_ 1024
#define H_ 16
#define HD_ 64
#define O_ 1152   // C + 2*HD

#define NX  (B_ * T_ * C_)      // 4194304
#define NW1 (O_ * C_)           // 1179648
#define NW2 (C_ * C_)           // 1048576

// softmax runs in exp2 domain: Q pre-scale = (1/8) * log2(e)
#define QSCALE 0.1803368801111244f

typedef __attribute__((ext_vector_type(8))) short bf16x8;
typedef __attribute__((ext_vector_type(4))) float f32x4;
typedef __attribute__((ext_vector_type(16))) float f32x16;
typedef __attribute__((ext_vector_type(4))) unsigned u32x4;
typedef __attribute__((ext_vector_type(2))) unsigned u32x2;

__device__ inline short f2bf(float f) {
    union { float f; unsigned u; } v; v.f = f;
    unsigned r = v.u + 0x7FFFu + ((v.u >> 16) & 1u);
    return (short)(r >> 16);
}
__device__ inline float bf2f(short s) {
    union { unsigned u; float f; } v; v.u = ((unsigned)(unsigned short)s) << 16;
    return v.f;
}
// native 2^x (v_exp_f32)
__device__ inline float exp2fast(float x) { return __builtin_amdgcn_exp2f(x); }
// packed bf16(lo) | bf16(hi)<<16, RNE
__device__ inline unsigned cvtpk(float lo, float hi) {
    unsigned r;
    asm("v_cvt_pk_bf16_f32 %0, %1, %2" : "=v"(r) : "v"(lo), "v"(hi));
    return r;
}
// permlane32_swap via builtin (hazard-safe: compiler inserts the required
// VALU->permlane wait states; raw inline asm did not - round 10 failure).
__device__ inline u32x2 pswap(unsigned a, unsigned b) {
    return __builtin_amdgcn_permlane32_swap(a, b, false, false);
}
// cross-half (lane^32) max/add, direction-agnostic
__device__ inline float xmax32(float x) {
    u32x2 r = pswap(__float_as_uint(x), __float_as_uint(x));
    return fmaxf(__uint_as_float(r[0]), __uint_as_float(r[1]));
}
__device__ inline float xadd32(float x) {
    u32x2 r = pswap(__float_as_uint(x), __float_as_uint(x));
    return __uint_as_float(r[0]) + __uint_as_float(r[1]);
}

// async global -> LDS, 16 B per lane (wave-uniform LDS base + lane*16)
#define GLL16(gp, lp) __builtin_amdgcn_global_load_lds( \
    (const __attribute__((address_space(1))) unsigned int*)(gp), \
    (__attribute__((address_space(3))) unsigned int*)(lp), 16, 0, 0)

// -------- f32 -> bf16 pre-conversion of x, Wqkv, Wproj (one launch) --------
__global__ __launch_bounds__(256) void cvt_bf16(const float* __restrict__ x,
        const float* __restrict__ w1, const float* __restrict__ w2,
        short* __restrict__ xb, short* __restrict__ w1b, short* __restrict__ w2b) {
    size_t i = ((size_t)blockIdx.x * 256 + threadIdx.x) * 8;
    const float* src; short* dst; size_t off;
    if (i < (size_t)NX)              { src = x;  dst = xb;  off = i; }
    else if (i < (size_t)NX + NW1)   { src = w1; dst = w1b; off = i - NX; }
    else                             { src = w2; dst = w2b; off = i - NX - NW1; }
    f32x4 a = *(const f32x4*)(src + off);
    f32x4 b = *(const f32x4*)(src + off + 4);
    bf16x8 r;
    r[0] = f2bf(a[0]); r[1] = f2bf(a[1]); r[2] = f2bf(a[2]); r[3] = f2bf(a[3]);
    r[4] = f2bf(b[0]); r[5] = f2bf(b[1]); r[6] = f2bf(b[2]); r[7] = f2bf(b[3]);
    *(bf16x8*)(dst + off) = r;
}

// C(M,N) = A(M,K) * B(N,K)^T, bf16 inputs, fp32 accum.
// v9 (round-16, kept): 128x64 block tile, LDS double-buffer, one barrier per
// k-step; global_load_lds width=16. 4 waves (2x2), wave = 64x32.
template <bool OUT_BF16>
__global__ __launch_bounds__(256) void gemm_bt(const short* __restrict__ A,
                                               const short* __restrict__ Bm,
                                               void* __restrict__ Cv,
                                               int M, int N, int K) {
    __shared__ short lA[2][128 * 32];   // 16 KB
    __shared__ short lB[2][64 * 32];    //  8 KB
    int ntn = N >> 6;
    int nwg = (M >> 7) * ntn;
    int cpx = nwg >> 3;                         // grids are %8 == 0
    int bid = (int)blockIdx.x;
    int swz = (bid % 8) * cpx + bid / 8;        // bijective XCD swizzle
    int m0 = (swz / ntn) << 7;
    int n0 = (swz % ntn) << 6;
    int t = threadIdx.x;
    int wid = t >> 6, l = t & 63;
    int wr = wid >> 1, wc = wid & 1;
    int c = l & 15, g = l >> 4;

    const short* gA0 = A + (size_t)(m0 + (t >> 2)) * K + (t & 3) * 8;
    const short* gA1 = gA0 + (size_t)64 * K;
    const short* gB0 = Bm + (size_t)(n0 + (t >> 2)) * K + (t & 3) * 8;

    int nstep = K >> 5;
    f32x4 acc[4][2] = {};
    int cur = 0;
    GLL16(gA0, &lA[0][t * 8]);
    GLL16(gA1, &lA[0][64 * 32 + t * 8]);
    GLL16(gB0, &lB[0][t * 8]);
    for (int it = 0; it < nstep; it++) {
        __syncthreads();                        // drains stage into lX[cur]
        if (it + 1 < nstep) {                   // stage next, overlapped
            int k = (it + 1) << 5;
            GLL16(gA0 + k, &lA[cur ^ 1][t * 8]);
            GLL16(gA1 + k, &lA[cur ^ 1][64 * 32 + t * 8]);
            GLL16(gB0 + k, &lB[cur ^ 1][t * 8]);
        }
        const short* lap = &lA[cur][(wr * 64 + c) * 32 + g * 8];
        const short* lbp = &lB[cur][(wc * 32 + c) * 32 + g * 8];
        bf16x8 a[4], b[2];
        #pragma unroll
        for (int i = 0; i < 4; i++) a[i] = *(const bf16x8*)(lap + i * 16 * 32);
        #pragma unroll
        for (int j = 0; j < 2; j++) b[j] = *(const bf16x8*)(lbp + j * 16 * 32);
        #pragma unroll
        for (int i = 0; i < 4; i++)
            #pragma unroll
            for (int j = 0; j < 2; j++)
                acc[i][j] = __builtin_amdgcn_mfma_f32_16x16x32_bf16(a[i], b[j], acc[i][j], 0, 0, 0);
        cur ^= 1;
    }

    #pragma unroll
    for (int i = 0; i < 4; i++)
        #pragma unroll
        for (int j = 0; j < 2; j++)
            #pragma unroll
            for (int r = 0; r < 4; r++) {
                int rr = m0 + wr * 64 + i * 16 + g * 4 + r;   // C/D row = (l>>4)*4 + reg
                int cc = n0 + wc * 32 + j * 16 + c;           // C/D col = l&15
                if (OUT_BF16)
                    ((short*)Cv)[(size_t)rr * N + cc] = f2bf(acc[i][j][r]);
                else
                    ((float*)Cv)[(size_t)rr * N + cc] = acc[i][j][r];
            }
}

// Causal depthwise conv1d (K=3) + bias on bf16 qkv; splits -> Q (B,H,T,64,
// scaled QSCALE for exp2-domain softmax), K (B,T,64), V transposed (B,64,T).
__global__ __launch_bounds__(256) void conv_split(const short* __restrict__ qkv,
        const float* __restrict__ qw, const float* __restrict__ qb,
        const float* __restrict__ kw, const float* __restrict__ kbias,
        const float* __restrict__ vw, const float* __restrict__ vbias,
        short* __restrict__ Qs, short* __restrict__ Kb, short* __restrict__ Vt) {
    int idx = blockIdx.x * 256 + threadIdx.x;
    int ch = idx % O_;
    int bt = idx / O_;
    int t = bt % T_;
    int b = bt / T_;
    const short* p = qkv + (size_t)bt * O_ + ch;
    float x2 = bf2f(p[0]);
    float x1 = (t >= 1) ? bf2f(p[-O_]) : 0.f;
    float x0 = (t >= 2) ? bf2f(p[-2 * O_]) : 0.f;
    float w0, w1, w2, bias;
    if (ch < C_)             { w0 = qw[ch*3]; w1 = qw[ch*3+1]; w2 = qw[ch*3+2]; bias = qb[ch]; }
    else if (ch < C_ + HD_)  { int cc = ch - C_;       w0 = kw[cc*3]; w1 = kw[cc*3+1]; w2 = kw[cc*3+2]; bias = kbias[cc]; }
    else                     { int cc = ch - C_ - HD_; w0 = vw[cc*3]; w1 = vw[cc*3+1]; w2 = vw[cc*3+2]; bias = vbias[cc]; }
    float y = fmaf(x0, w0, fmaf(x1, w1, fmaf(x2, w2, bias)));
    if (ch < C_) {
        int h = ch >> 6, d = ch & 63;
        Qs[(((size_t)b * H_ + h) * T_ + t) * HD_ + d] = f2bf(y * QSCALE);
    } else if (ch < C_ + HD_) {
        Kb[((size_t)b * T_ + t) * HD_ + (ch - C_)] = f2bf(y);
    } else {
        Vt[((size_t)b * HD_ + (ch - C_ - HD_)) * T_ + t] = f2bf(y);
    }
}

// Flash-style causal MQA, v14 = v13 + KVB-128 ROUNDS: each barrier round
// stages TWO 64-row K/V subtiles (8 GLL16/thread) and processes both.
// Heaviest block: 32 -> 16 barrier rounds; the ~2.6k-cyc/round fixed cost
// (barrier skew + vmcnt drain) amortizes over 2x compute. LDS 64 KB,
// 2 blocks/CU. Same swizzled staging/read geometry as v13 (T2/m201).
// C/D layout (m74-verified): col=lane&31, row=(reg&3)+8*(reg>>2)+4*(lane>>5).
__global__ __launch_bounds__(256, 2) void attn_kernel(const short* __restrict__ Qs,
        const short* __restrict__ Kb, const short* __restrict__ Vt,
        short* __restrict__ Y) {
    __shared__ short KL[2][2][64 * 64];   // 32 KB (2 bufs x 2 subtiles x 8 KB)
    __shared__ short VL[2][2][64 * 64];   // 32 KB
    int n = (int)blockIdx.x;                   // 0..511
    int half = n >> 8;
    int n2 = n & 255;
    int y = n2 >> 5;                           // 0..7: b*4 + hq
    int qx = n2 & 31;
    int qt = half ? qx : 63 - qx;              // heavy first
    int b = y >> 2;
    int hq = y & 3;
    int t = threadIdx.x;
    int wid = t >> 6, l = t & 63;
    int ql = l & 31, hi = l >> 5;
    int h = hq * 4 + wid;
    int bh = b * H_ + h;
    int qbase = qt * 32;
    int qi = qbase + ql;

    // Q B-fragments (col=q=ql, d=hi*8+j), per-wave head
    const short* Qp = Qs + ((size_t)bh * T_ + qi) * HD_ + hi * 8;
    bf16x8 qf[4];
    #pragma unroll
    for (int s = 0; s < 4; s++) qf[s] = *(const bf16x8*)(Qp + s * 16);

    f32x16 Oa0 = {}, Oa1 = {};                 // O^T, d-blocks [0,32) and [32,64)
    float mrow = -1e30f, lsum = 0.f;

    const short* Kbase = Kb + (size_t)b * T_ * HD_;
    const short* Vbase = Vt + (size_t)b * HD_ * T_;

    // ---- staging geometry: thread t -> row krow = t>>3, col16 = t&7 ----
    // LDS linear slot (row, s16) holds global col16 = s16 ^ (row&7)  (m201).
    int krow = t >> 3;
    int sc = ((t & 7) ^ (krow & 7)) * 8;       // pre-swizzled source col (elems)
    const short* KgA = Kbase + (size_t)krow * HD_ + sc;   // + kt0*HD at stage
    const short* VgA = Vbase + (size_t)krow * T_ + sc;    // + kt0 at stage
    int t8 = t * 8;                             // LDS short index (t*16 bytes)

    auto STAGE1 = [&](short* Kd, short* Vd, int kt0) {
        GLL16(KgA + (size_t)kt0 * HD_, Kd + t8);
        GLL16(KgA + (size_t)(kt0 + 32) * HD_, Kd + 2048 + t8);
        GLL16(VgA + kt0, Vd + t8);
        GLL16(VgA + kt0 + (size_t)32 * T_, Vd + 2048 + t8);
    };

    // process one 64-row subtile from LDS
    auto PROC = [&](const short* Kt, const short* Vtl, int kt0) {
        // ---- S^T from swizzled LDS K ----
        f32x16 sv0 = {}, sv1 = {};
        #pragma unroll
        for (int s = 0; s < 4; s++) {
            bf16x8 ka = *(const bf16x8*)&Kt[ql * 64 + (((s * 2 + hi) ^ (ql & 7)) * 8)];
            sv0 = __builtin_amdgcn_mfma_f32_32x32x16_bf16(ka, qf[s], sv0, 0, 0, 0);
        }
        #pragma unroll
        for (int s = 0; s < 4; s++) {
            bf16x8 ka = *(const bf16x8*)&Kt[(32 + ql) * 64 + (((s * 2 + hi) ^ (ql & 7)) * 8)];
            sv1 = __builtin_amdgcn_mfma_f32_32x32x16_bf16(ka, qf[s], sv1, 0, 0, 0);
        }
        // ---- causal mask (diagonal tile only; scale folded into Q) ----
        if (kt0 + 64 > qbase) {
            #pragma unroll
            for (int r = 0; r < 16; r++) {
                int kl = (r & 3) + 8 * (r >> 2) + 4 * hi;
                if (kt0 + kl > qi)      sv0[r] = -1e30f;
                if (kt0 + 32 + kl > qi) sv1[r] = -1e30f;
            }
        }
        // ---- row max: depth-5 tree + cross-half combine ----
        float t8v[8];
        #pragma unroll
        for (int r = 0; r < 8; r++)
            t8v[r] = fmaxf(fmaxf(sv0[r], sv0[r + 8]), fmaxf(sv1[r], sv1[r + 8]));
        float pmax = fmaxf(fmaxf(fmaxf(t8v[0], t8v[4]), fmaxf(t8v[1], t8v[5])),
                           fmaxf(fmaxf(t8v[2], t8v[6]), fmaxf(t8v[3], t8v[7])));
        pmax = xmax32(pmax);
        // ---- defer-max (T13): rescale only when max grew past THR=8 ----
        if (!__all(pmax <= mrow + 8.f)) {
            float nm = fmaxf(mrow, pmax);
            float alpha = exp2fast(mrow - nm);
            mrow = nm;
            lsum *= alpha;
            #pragma unroll
            for (int r = 0; r < 16; r++) { Oa0[r] *= alpha; Oa1[r] *= alpha; }
        }
        // ---- P = exp2(S - m); sum via depth-5 tree + cross-half add ----
        #pragma unroll
        for (int r = 0; r < 16; r++) sv0[r] = exp2fast(sv0[r] - mrow);
        #pragma unroll
        for (int r = 0; r < 16; r++) sv1[r] = exp2fast(sv1[r] - mrow);
        float s8[8];
        #pragma unroll
        for (int r = 0; r < 8; r++)
            s8[r] = (sv0[r] + sv0[r + 8]) + (sv1[r] + sv1[r + 8]);
        float psum = ((s8[0] + s8[4]) + (s8[1] + s8[5])) +
                     ((s8[2] + s8[6]) + (s8[3] + s8[7]));
        lsum += xadd32(psum);
        // ---- P redistribution (cvt_pk + permlane32_swap) + PV from LDS V ----
        #pragma unroll
        for (int sub = 0; sub < 2; sub++) {
            #pragma unroll
            for (int hh = 0; hh < 2; hh++) {
                unsigned X0, X1, X2, X3;
                if (sub == 0) {
                    X0 = cvtpk(sv0[hh * 8 + 0], sv0[hh * 8 + 1]);
                    X1 = cvtpk(sv0[hh * 8 + 2], sv0[hh * 8 + 3]);
                    X2 = cvtpk(sv0[hh * 8 + 4], sv0[hh * 8 + 5]);
                    X3 = cvtpk(sv0[hh * 8 + 6], sv0[hh * 8 + 7]);
                } else {
                    X0 = cvtpk(sv1[hh * 8 + 0], sv1[hh * 8 + 1]);
                    X1 = cvtpk(sv1[hh * 8 + 2], sv1[hh * 8 + 3]);
                    X2 = cvtpk(sv1[hh * 8 + 4], sv1[hh * 8 + 5]);
                    X3 = cvtpk(sv1[hh * 8 + 6], sv1[hh * 8 + 7]);
                }
                u32x2 r02 = pswap(X0, X2);
                u32x2 r13 = pswap(X1, X3);
                union { u32x4 u; bf16x8 v; } pw;
                pw.u[0] = r02[0];   // k elems (hi*8 + 0,1)
                pw.u[1] = r13[0];   // k elems (hi*8 + 2,3)
                pw.u[2] = r02[1];   // k elems (hi*8 + 4,5)
                pw.u[3] = r13[1];   // k elems (hi*8 + 6,7)
                int u = sub * 2 + hh;           // V col16 = u*2 + hi
                bf16x8 va0 = *(const bf16x8*)&Vtl[ql * 64 + (((u * 2 + hi) ^ (ql & 7)) * 8)];
                bf16x8 va1 = *(const bf16x8*)&Vtl[(32 + ql) * 64 + (((u * 2 + hi) ^ (ql & 7)) * 8)];
                Oa0 = __builtin_amdgcn_mfma_f32_32x32x16_bf16(va0, pw.v, Oa0, 0, 0, 0);
                Oa1 = __builtin_amdgcn_mfma_f32_32x32x16_bf16(va1, pw.v, Oa1, 0, 0, 0);
            }
        }
    };

    int nt = (qt >> 1) + 1;                    // 64-row tiles
    int nr = (nt + 1) >> 1;                    // 128-row rounds
    int cur = 0;
    STAGE1(KL[0][0], VL[0][0], 0);
    STAGE1(KL[0][1], VL[0][1], 64);
    for (int r = 0; r < nr; r++) {
        __syncthreads();                        // buf[cur] ready (vmcnt drained)
        if (r + 1 < nr) {
            int base = (r + 1) * 128;
            STAGE1(KL[cur ^ 1][0], VL[cur ^ 1][0], base);
            STAGE1(KL[cur ^ 1][1], VL[cur ^ 1][1], base + 64);
        }
        PROC(KL[cur][0], VL[cur][0], r * 128);
        if (r * 2 + 1 < nt)
            PROC(KL[cur][1], VL[cur][1], r * 128 + 64);
        cur ^= 1;
    }
    // ---- epilogue: normalize, write one Y-row segment per lane ----
    float inv = 1.f / lsum;
    size_t orow = ((size_t)b * T_ + qi) * C_ + h * HD_;
    #pragma unroll
    for (int r = 0; r < 16; r += 2) {
        int d = (r & 3) + 8 * (r >> 2) + 4 * hi;       // (r,r+1)->(d,d+1)
        *(unsigned*)(Y + orow + d)      = cvtpk(Oa0[r] * inv, Oa0[r + 1] * inv);
        *(unsigned*)(Y + orow + 32 + d) = cvtpk(Oa1[r] * inv, Oa1[r + 1] * inv);
    }
}

extern "C" void kernel_launch(void* const* d_in, const int* in_sizes, int n_in,
                              void* d_out, int out_size, void* d_ws, size_t ws_size,
                              hipStream_t stream) {
    const float* x     = (const float*)d_in[0];
    const float* Wqkv  = (const float*)d_in[1];
    const float* qw    = (const float*)d_in[2];
    const float* qb    = (const float*)d_in[3];
    const float* kw    = (const float*)d_in[4];
    const float* kbias = (const float*)d_in[5];
    const float* vw    = (const float*)d_in[6];
    const float* vbias = (const float*)d_in[7];
    const float* Wproj = (const float*)d_in[8];

    char* ws = (char*)d_ws;
    short* xb     = (short*)ws;                    //  8388608 B (reused as Ybf later)
    short* Wqkvb  = (short*)(ws + 8388608);        //  2359296 B
    short* Wprojb = (short*)(ws + 10747904);       //  2097152 B
    short* qkvb   = (short*)(ws + 12845056);       //  9437184 B
    short* Qsc    = (short*)(ws + 22282240);       //  8388608 B
    short* Kbf    = (short*)(ws + 30670848);       //   524288 B
    short* Vtr    = (short*)(ws + 31195136);       //   524288 B  (total 31.7 MB)
    short* Ybf    = xb;                            // x dead after gemm1

    const int M = B_ * T_;  // 4096

    // 0) f32 -> bf16: x, Wqkv, Wproj
    cvt_bf16<<<dim3(3136), 256, 0, stream>>>(x, Wqkv, Wproj, xb, Wqkvb, Wprojb);

    // 1) qkv = x @ Wqkv^T  (bf16 out)   grid 32*18 = 576 (%8==0)
    gemm_bt<true><<<dim3((M / 128) * (O_ / 64)), 256, 0, stream>>>(
        xb, Wqkvb, qkvb, M, O_, C_);

    // 2) causal dwconv + split + scale + V-transpose
    conv_split<<<dim3((B_ * T_ * O_) / 256), 256, 0, stream>>>(
        qkvb, qw, qb, kw, kbias, vw, vbias, Qsc, Kbf, Vtr);

    // 3) causal MQA attention -> y (B,T,C) bf16   (LDS-shared K/V, 128-row rounds)
    attn_kernel<<<dim3(512), 256, 0, stream>>>(Qsc, Kbf, Vtr, Ybf);

    // 4) out = y @ Wproj^T -> f32 d_out   grid 32*16 = 512 (%8==0)
    gemm_bt<false><<<dim3((M / 128) * (C_ / 64)), 256, 0, stream>>>(
        Ybf, Wprojb, (float*)d_out, M, C_, C_);
}

// Round 22
// 99.475 us; speedup vs baseline: 1.5044x; 1.0923x over previous
//
#include <hip/hip_runtime.h>
#include <hip/hip_bf16.h>

#define B_ 2
#define T_ 2048
#define C_ 1024
#define H_ 16
#define HD_ 64
#define O_ 1152   // C + 2*HD

#define NX  (B_ * T_ * C_)      // 4194304
#define NW1 (O_ * C_)           // 1179648
#define NW2 (C_ * C_)           // 1048576

// softmax runs in exp2 domain: Q pre-scale = (1/8) * log2(e)
#define QSCALE 0.1803368801111244f

typedef __attribute__((ext_vector_type(8))) short bf16x8;
typedef __attribute__((ext_vector_type(4))) float f32x4;
typedef __attribute__((ext_vector_type(16))) float f32x16;
typedef __attribute__((ext_vector_type(4))) unsigned u32x4;
typedef __attribute__((ext_vector_type(2))) unsigned u32x2;

__device__ inline short f2bf(float f) {
    union { float f; unsigned u; } v; v.f = f;
    unsigned r = v.u + 0x7FFFu + ((v.u >> 16) & 1u);
    return (short)(r >> 16);
}
__device__ inline float bf2f(short s) {
    union { unsigned u; float f; } v; v.u = ((unsigned)(unsigned short)s) << 16;
    return v.f;
}
// native 2^x (v_exp_f32)
__device__ inline float exp2fast(float x) { return __builtin_amdgcn_exp2f(x); }
// packed bf16(lo) | bf16(hi)<<16, RNE
__device__ inline unsigned cvtpk(float lo, float hi) {
    unsigned r;
    asm("v_cvt_pk_bf16_f32 %0, %1, %2" : "=v"(r) : "v"(lo), "v"(hi));
    return r;
}
// permlane32_swap via builtin (hazard-safe: compiler inserts the required
// VALU->permlane wait states; raw inline asm did not - round 10 failure).
__device__ inline u32x2 pswap(unsigned a, unsigned b) {
    return __builtin_amdgcn_permlane32_swap(a, b, false, false);
}
// cross-half (lane^32) max/add, direction-agnostic
__device__ inline float xmax32(float x) {
    u32x2 r = pswap(__float_as_uint(x), __float_as_uint(x));
    return fmaxf(__uint_as_float(r[0]), __uint_as_float(r[1]));
}
__device__ inline float xadd32(float x) {
    u32x2 r = pswap(__float_as_uint(x), __float_as_uint(x));
    return __uint_as_float(r[0]) + __uint_as_float(r[1]);
}

// async global -> LDS, 16 B per lane (wave-uniform LDS base + lane*16)
#define GLL16(gp, lp) __builtin_amdgcn_global_load_lds( \
    (const __attribute__((address_space(1))) unsigned int*)(gp), \
    (__attribute__((address_space(3))) unsigned int*)(lp), 16, 0, 0)

// -------- f32 -> bf16 pre-conversion of x, Wqkv, Wproj (one launch) --------
__global__ __launch_bounds__(256) void cvt_bf16(const float* __restrict__ x,
        const float* __restrict__ w1, const float* __restrict__ w2,
        short* __restrict__ xb, short* __restrict__ w1b, short* __restrict__ w2b) {
    size_t i = ((size_t)blockIdx.x * 256 + threadIdx.x) * 8;
    const float* src; short* dst; size_t off;
    if (i < (size_t)NX)              { src = x;  dst = xb;  off = i; }
    else if (i < (size_t)NX + NW1)   { src = w1; dst = w1b; off = i - NX; }
    else                             { src = w2; dst = w2b; off = i - NX - NW1; }
    f32x4 a = *(const f32x4*)(src + off);
    f32x4 b = *(const f32x4*)(src + off + 4);
    bf16x8 r;
    r[0] = f2bf(a[0]); r[1] = f2bf(a[1]); r[2] = f2bf(a[2]); r[3] = f2bf(a[3]);
    r[4] = f2bf(b[0]); r[5] = f2bf(b[1]); r[6] = f2bf(b[2]); r[7] = f2bf(b[3]);
    *(bf16x8*)(dst + off) = r;
}

// C(M,N) = A(M,K) * B(N,K)^T, bf16 inputs, fp32 accum.
// v10: 128x64 block tile, BK=64 (16 barrier rounds vs 32 -- halves the
// stage-drain + barrier fixed cost), LDS double-buffer (48 KB, 2 blocks/CU),
// m201 XOR-swizzle on LDS (pre-swizzled global source + swizzled ds_read;
// fixes the ~8-way bank aliasing of the old linear 64B-pitch layout).
// 4 waves (2x2), each wave 64x32, 16 MFMA per k-round.
template <bool OUT_BF16>
__global__ __launch_bounds__(256) void gemm_bt(const short* __restrict__ A,
                                               const short* __restrict__ Bm,
                                               void* __restrict__ Cv,
                                               int M, int N, int K) {
    __shared__ short lA[2][128 * 64];   // 32 KB
    __shared__ short lB[2][64 * 64];    // 16 KB
    int ntn = N >> 6;
    int nwg = (M >> 7) * ntn;
    int cpx = nwg >> 3;                         // grids are %8 == 0
    int bid = (int)blockIdx.x;
    int swz = (bid % 8) * cpx + bid / 8;        // bijective XCD swizzle
    int m0 = (swz / ntn) << 7;
    int n0 = (swz % ntn) << 6;
    int t = threadIdx.x;
    int wid = t >> 6, l = t & 63;
    int wr = wid >> 1, wc = wid & 1;
    int c = l & 15, g = l >> 4;

    // staging: A tile 128x64 = 1024 16B-chunks (4/thread); B 64x64 = 512 (2/thread)
    // LDS slot (row, sl) holds global chunk sl ^ (row&7)  (m201 both-sides swizzle)
    const short* gAsrc[4];
    int lAoff[4];
    #pragma unroll
    for (int i = 0; i < 4; i++) {
        int cidx = t + i * 256;
        int row = cidx >> 3, sl = cidx & 7;
        gAsrc[i] = A + (size_t)(m0 + row) * K + ((sl ^ (row & 7)) * 8);
        lAoff[i] = cidx * 8;
    }
    const short* gBsrc[2];
    int lBoff[2];
    #pragma unroll
    for (int i = 0; i < 2; i++) {
        int cidx = t + i * 256;
        int row = cidx >> 3, sl = cidx & 7;
        gBsrc[i] = Bm + (size_t)(n0 + row) * K + ((sl ^ (row & 7)) * 8);
        lBoff[i] = cidx * 8;
    }

    int nstep = K >> 6;                          // 16 for K=1024
    f32x4 acc[4][2] = {};
    int cur = 0;
    #pragma unroll
    for (int i = 0; i < 4; i++) GLL16(gAsrc[i], &lA[0][lAoff[i]]);
    #pragma unroll
    for (int i = 0; i < 2; i++) GLL16(gBsrc[i], &lB[0][lBoff[i]]);
    for (int it = 0; it < nstep; it++) {
        __syncthreads();                        // drains stage into lX[cur]
        if (it + 1 < nstep) {                   // stage next, overlapped
            int k = (it + 1) << 6;
            #pragma unroll
            for (int i = 0; i < 4; i++) GLL16(gAsrc[i] + k, &lA[cur ^ 1][lAoff[i]]);
            #pragma unroll
            for (int i = 0; i < 2; i++) GLL16(gBsrc[i] + k, &lB[cur ^ 1][lBoff[i]]);
        }
        #pragma unroll
        for (int ks = 0; ks < 2; ks++) {
            bf16x8 a[4], b[2];
            #pragma unroll
            for (int i = 0; i < 4; i++) {
                int row = wr * 64 + i * 16 + c;
                a[i] = *(const bf16x8*)&lA[cur][row * 64 + (((ks * 4 + g) ^ (row & 7)) * 8)];
            }
            #pragma unroll
            for (int j = 0; j < 2; j++) {
                int row = wc * 32 + j * 16 + c;
                b[j] = *(const bf16x8*)&lB[cur][row * 64 + (((ks * 4 + g) ^ (row & 7)) * 8)];
            }
            #pragma unroll
            for (int i = 0; i < 4; i++)
                #pragma unroll
                for (int j = 0; j < 2; j++)
                    acc[i][j] = __builtin_amdgcn_mfma_f32_16x16x32_bf16(a[i], b[j], acc[i][j], 0, 0, 0);
        }
        cur ^= 1;
    }

    #pragma unroll
    for (int i = 0; i < 4; i++)
        #pragma unroll
        for (int j = 0; j < 2; j++)
            #pragma unroll
            for (int r = 0; r < 4; r++) {
                int rr = m0 + wr * 64 + i * 16 + g * 4 + r;   // C/D row = (l>>4)*4 + reg
                int cc = n0 + wc * 32 + j * 16 + c;           // C/D col = l&15
                if (OUT_BF16)
                    ((short*)Cv)[(size_t)rr * N + cc] = f2bf(acc[i][j][r]);
                else
                    ((float*)Cv)[(size_t)rr * N + cc] = acc[i][j][r];
            }
}

// Causal depthwise conv1d (K=3) + bias on bf16 qkv; splits -> Q (B,H,T,64,
// scaled QSCALE for exp2-domain softmax), K (B,T,64), V transposed (B,64,T).
__global__ __launch_bounds__(256) void conv_split(const short* __restrict__ qkv,
        const float* __restrict__ qw, const float* __restrict__ qb,
        const float* __restrict__ kw, const float* __restrict__ kbias,
        const float* __restrict__ vw, const float* __restrict__ vbias,
        short* __restrict__ Qs, short* __restrict__ Kb, short* __restrict__ Vt) {
    int idx = blockIdx.x * 256 + threadIdx.x;
    int ch = idx % O_;
    int bt = idx / O_;
    int t = bt % T_;
    int b = bt / T_;
    const short* p = qkv + (size_t)bt * O_ + ch;
    float x2 = bf2f(p[0]);
    float x1 = (t >= 1) ? bf2f(p[-O_]) : 0.f;
    float x0 = (t >= 2) ? bf2f(p[-2 * O_]) : 0.f;
    float w0, w1, w2, bias;
    if (ch < C_)             { w0 = qw[ch*3]; w1 = qw[ch*3+1]; w2 = qw[ch*3+2]; bias = qb[ch]; }
    else if (ch < C_ + HD_)  { int cc = ch - C_;       w0 = kw[cc*3]; w1 = kw[cc*3+1]; w2 = kw[cc*3+2]; bias = kbias[cc]; }
    else                     { int cc = ch - C_ - HD_; w0 = vw[cc*3]; w1 = vw[cc*3+1]; w2 = vw[cc*3+2]; bias = vbias[cc]; }
    float y = fmaf(x0, w0, fmaf(x1, w1, fmaf(x2, w2, bias)));
    if (ch < C_) {
        int h = ch >> 6, d = ch & 63;
        Qs[(((size_t)b * H_ + h) * T_ + t) * HD_ + d] = f2bf(y * QSCALE);
    } else if (ch < C_ + HD_) {
        Kb[((size_t)b * T_ + t) * HD_ + (ch - C_)] = f2bf(y);
    } else {
        Vt[((size_t)b * HD_ + (ch - C_ - HD_)) * T_ + t] = f2bf(y);
    }
}

// Flash-style causal MQA, v14 (round-20, kept): LDS-shared K/V across 4 heads,
// 128-row barrier rounds, double-buffered, XOR-swizzled staging/reads,
// swapped QK^T + exp2 softmax + tree reductions + T12/T13.
// C/D layout (m74-verified): col=lane&31, row=(reg&3)+8*(reg>>2)+4*(lane>>5).
__global__ __launch_bounds__(256, 2) void attn_kernel(const short* __restrict__ Qs,
        const short* __restrict__ Kb, const short* __restrict__ Vt,
        short* __restrict__ Y) {
    __shared__ short KL[2][2][64 * 64];   // 32 KB (2 bufs x 2 subtiles x 8 KB)
    __shared__ short VL[2][2][64 * 64];   // 32 KB
    int n = (int)blockIdx.x;                   // 0..511
    int half = n >> 8;
    int n2 = n & 255;
    int y = n2 >> 5;                           // 0..7: b*4 + hq
    int qx = n2 & 31;
    int qt = half ? qx : 63 - qx;              // heavy first
    int b = y >> 2;
    int hq = y & 3;
    int t = threadIdx.x;
    int wid = t >> 6, l = t & 63;
    int ql = l & 31, hi = l >> 5;
    int h = hq * 4 + wid;
    int bh = b * H_ + h;
    int qbase = qt * 32;
    int qi = qbase + ql;

    // Q B-fragments (col=q=ql, d=hi*8+j), per-wave head
    const short* Qp = Qs + ((size_t)bh * T_ + qi) * HD_ + hi * 8;
    bf16x8 qf[4];
    #pragma unroll
    for (int s = 0; s < 4; s++) qf[s] = *(const bf16x8*)(Qp + s * 16);

    f32x16 Oa0 = {}, Oa1 = {};                 // O^T, d-blocks [0,32) and [32,64)
    float mrow = -1e30f, lsum = 0.f;

    const short* Kbase = Kb + (size_t)b * T_ * HD_;
    const short* Vbase = Vt + (size_t)b * HD_ * T_;

    // ---- staging geometry: thread t -> row krow = t>>3, col16 = t&7 ----
    // LDS linear slot (row, s16) holds global col16 = s16 ^ (row&7)  (m201).
    int krow = t >> 3;
    int sc = ((t & 7) ^ (krow & 7)) * 8;       // pre-swizzled source col (elems)
    const short* KgA = Kbase + (size_t)krow * HD_ + sc;   // + kt0*HD at stage
    const short* VgA = Vbase + (size_t)krow * T_ + sc;    // + kt0 at stage
    int t8 = t * 8;                             // LDS short index (t*16 bytes)

    auto STAGE1 = [&](short* Kd, short* Vd, int kt0) {
        GLL16(KgA + (size_t)kt0 * HD_, Kd + t8);
        GLL16(KgA + (size_t)(kt0 + 32) * HD_, Kd + 2048 + t8);
        GLL16(VgA + kt0, Vd + t8);
        GLL16(VgA + kt0 + (size_t)32 * T_, Vd + 2048 + t8);
    };

    // process one 64-row subtile from LDS
    auto PROC = [&](const short* Kt, const short* Vtl, int kt0) {
        // ---- S^T from swizzled LDS K ----
        f32x16 sv0 = {}, sv1 = {};
        #pragma unroll
        for (int s = 0; s < 4; s++) {
            bf16x8 ka = *(const bf16x8*)&Kt[ql * 64 + (((s * 2 + hi) ^ (ql & 7)) * 8)];
            sv0 = __builtin_amdgcn_mfma_f32_32x32x16_bf16(ka, qf[s], sv0, 0, 0, 0);
        }
        #pragma unroll
        for (int s = 0; s < 4; s++) {
            bf16x8 ka = *(const bf16x8*)&Kt[(32 + ql) * 64 + (((s * 2 + hi) ^ (ql & 7)) * 8)];
            sv1 = __builtin_amdgcn_mfma_f32_32x32x16_bf16(ka, qf[s], sv1, 0, 0, 0);
        }
        // ---- causal mask (diagonal tile only; scale folded into Q) ----
        if (kt0 + 64 > qbase) {
            #pragma unroll
            for (int r = 0; r < 16; r++) {
                int kl = (r & 3) + 8 * (r >> 2) + 4 * hi;
                if (kt0 + kl > qi)      sv0[r] = -1e30f;
                if (kt0 + 32 + kl > qi) sv1[r] = -1e30f;
            }
        }
        // ---- row max: depth-5 tree + cross-half combine ----
        float t8v[8];
        #pragma unroll
        for (int r = 0; r < 8; r++)
            t8v[r] = fmaxf(fmaxf(sv0[r], sv0[r + 8]), fmaxf(sv1[r], sv1[r + 8]));
        float pmax = fmaxf(fmaxf(fmaxf(t8v[0], t8v[4]), fmaxf(t8v[1], t8v[5])),
                           fmaxf(fmaxf(t8v[2], t8v[6]), fmaxf(t8v[3], t8v[7])));
        pmax = xmax32(pmax);
        // ---- defer-max (T13): rescale only when max grew past THR=8 ----
        if (!__all(pmax <= mrow + 8.f)) {
            float nm = fmaxf(mrow, pmax);
            float alpha = exp2fast(mrow - nm);
            mrow = nm;
            lsum *= alpha;
            #pragma unroll
            for (int r = 0; r < 16; r++) { Oa0[r] *= alpha; Oa1[r] *= alpha; }
        }
        // ---- P = exp2(S - m); sum via depth-5 tree + cross-half add ----
        #pragma unroll
        for (int r = 0; r < 16; r++) sv0[r] = exp2fast(sv0[r] - mrow);
        #pragma unroll
        for (int r = 0; r < 16; r++) sv1[r] = exp2fast(sv1[r] - mrow);
        float s8[8];
        #pragma unroll
        for (int r = 0; r < 8; r++)
            s8[r] = (sv0[r] + sv0[r + 8]) + (sv1[r] + sv1[r + 8]);
        float psum = ((s8[0] + s8[4]) + (s8[1] + s8[5])) +
                     ((s8[2] + s8[6]) + (s8[3] + s8[7]));
        lsum += xadd32(psum);
        // ---- P redistribution (cvt_pk + permlane32_swap) + PV from LDS V ----
        #pragma unroll
        for (int sub = 0; sub < 2; sub++) {
            #pragma unroll
            for (int hh = 0; hh < 2; hh++) {
                unsigned X0, X1, X2, X3;
                if (sub == 0) {
                    X0 = cvtpk(sv0[hh * 8 + 0], sv0[hh * 8 + 1]);
                    X1 = cvtpk(sv0[hh * 8 + 2], sv0[hh * 8 + 3]);
                    X2 = cvtpk(sv0[hh * 8 + 4], sv0[hh * 8 + 5]);
                    X3 = cvtpk(sv0[hh * 8 + 6], sv0[hh * 8 + 7]);
                } else {
                    X0 = cvtpk(sv1[hh * 8 + 0], sv1[hh * 8 + 1]);
                    X1 = cvtpk(sv1[hh * 8 + 2], sv1[hh * 8 + 3]);
                    X2 = cvtpk(sv1[hh * 8 + 4], sv1[hh * 8 + 5]);
                    X3 = cvtpk(sv1[hh * 8 + 6], sv1[hh * 8 + 7]);
                }
                u32x2 r02 = pswap(X0, X2);
                u32x2 r13 = pswap(X1, X3);
                union { u32x4 u; bf16x8 v; } pw;
                pw.u[0] = r02[0];   // k elems (hi*8 + 0,1)
                pw.u[1] = r13[0];   // k elems (hi*8 + 2,3)
                pw.u[2] = r02[1];   // k elems (hi*8 + 4,5)
                pw.u[3] = r13[1];   // k elems (hi*8 + 6,7)
                int u = sub * 2 + hh;           // V col16 = u*2 + hi
                bf16x8 va0 = *(const bf16x8*)&Vtl[ql * 64 + (((u * 2 + hi) ^ (ql & 7)) * 8)];
                bf16x8 va1 = *(const bf16x8*)&Vtl[(32 + ql) * 64 + (((u * 2 + hi) ^ (ql & 7)) * 8)];
                Oa0 = __builtin_amdgcn_mfma_f32_32x32x16_bf16(va0, pw.v, Oa0, 0, 0, 0);
                Oa1 = __builtin_amdgcn_mfma_f32_32x32x16_bf16(va1, pw.v, Oa1, 0, 0, 0);
            }
        }
    };

    int nt = (qt >> 1) + 1;                    // 64-row tiles
    int nr = (nt + 1) >> 1;                    // 128-row rounds
    int cur = 0;
    STAGE1(KL[0][0], VL[0][0], 0);
    STAGE1(KL[0][1], VL[0][1], 64);
    for (int r = 0; r < nr; r++) {
        __syncthreads();                        // buf[cur] ready (vmcnt drained)
        if (r + 1 < nr) {
            int base = (r + 1) * 128;
            STAGE1(KL[cur ^ 1][0], VL[cur ^ 1][0], base);
            STAGE1(KL[cur ^ 1][1], VL[cur ^ 1][1], base + 64);
        }
        PROC(KL[cur][0], VL[cur][0], r * 128);
        if (r * 2 + 1 < nt)
            PROC(KL[cur][1], VL[cur][1], r * 128 + 64);
        cur ^= 1;
    }
    // ---- epilogue: normalize, write one Y-row segment per lane ----
    float inv = 1.f / lsum;
    size_t orow = ((size_t)b * T_ + qi) * C_ + h * HD_;
    #pragma unroll
    for (int r = 0; r < 16; r += 2) {
        int d = (r & 3) + 8 * (r >> 2) + 4 * hi;       // (r,r+1)->(d,d+1)
        *(unsigned*)(Y + orow + d)      = cvtpk(Oa0[r] * inv, Oa0[r + 1] * inv);
        *(unsigned*)(Y + orow + 32 + d) = cvtpk(Oa1[r] * inv, Oa1[r + 1] * inv);
    }
}

extern "C" void kernel_launch(void* const* d_in, const int* in_sizes, int n_in,
                              void* d_out, int out_size, void* d_ws, size_t ws_size,
                              hipStream_t stream) {
    const float* x     = (const float*)d_in[0];
    const float* Wqkv  = (const float*)d_in[1];
    const float* qw    = (const float*)d_in[2];
    const float* qb    = (const float*)d_in[3];
    const float* kw    = (const float*)d_in[4];
    const float* kbias = (const float*)d_in[5];
    const float* vw    = (const float*)d_in[6];
    const float* vbias = (const float*)d_in[7];
    const float* Wproj = (const float*)d_in[8];

    char* ws = (char*)d_ws;
    short* xb     = (short*)ws;                    //  8388608 B (reused as Ybf later)
    short* Wqkvb  = (short*)(ws + 8388608);        //  2359296 B
    short* Wprojb = (short*)(ws + 10747904);       //  2097152 B
    short* qkvb   = (short*)(ws + 12845056);       //  9437184 B
    short* Qsc    = (short*)(ws + 22282240);       //  8388608 B
    short* Kbf    = (short*)(ws + 30670848);       //   524288 B
    short* Vtr    = (short*)(ws + 31195136);       //   524288 B  (total 31.7 MB)
    short* Ybf    = xb;                            // x dead after gemm1

    const int M = B_ * T_;  // 4096

    // 0) f32 -> bf16: x, Wqkv, Wproj
    cvt_bf16<<<dim3(3136), 256, 0, stream>>>(x, Wqkv, Wproj, xb, Wqkvb, Wprojb);

    // 1) qkv = x @ Wqkv^T  (bf16 out)   grid 32*18 = 576 (%8==0)
    gemm_bt<true><<<dim3((M / 128) * (O_ / 64)), 256, 0, stream>>>(
        xb, Wqkvb, qkvb, M, O_, C_);

    // 2) causal dwconv + split + scale + V-transpose
    conv_split<<<dim3((B_ * T_ * O_) / 256), 256, 0, stream>>>(
        qkvb, qw, qb, kw, kbias, vw, vbias, Qsc, Kbf, Vtr);

    // 3) causal MQA attention -> y (B,T,C) bf16   (LDS-shared K/V, 128-row rounds)
    attn_kernel<<<dim3(512), 256, 0, stream>>>(Qsc, Kbf, Vtr, Ybf);

    // 4) out = y @ Wproj^T -> f32 d_out   grid 32*16 = 512 (%8==0)
    gemm_bt<false><<<dim3((M / 128) * (C_ / 64)), 256, 0, stream>>>(
        Ybf, Wprojb, (float*)d_out, M, C_, C_);
}

// Round 23
// 91.382 us; speedup vs baseline: 1.6377x; 1.0886x over previous
//
#include <hip/hip_runtime.h>
#include <hip/hip_bf16.h>

#define B_ 2
#define T_ 2048
#define C_ 1024
#define H_ 16
#define HD_ 64
#define O_ 1152   // C + 2*HD

#define NX  (B_ * T_ * C_)      // 4194304
#define NW1 (O_ * C_)           // 1179648
#define NW2 (C_ * C_)           // 1048576

// softmax runs in exp2 domain: Q pre-scale = (1/8) * log2(e)
#define QSCALE 0.1803368801111244f

typedef __attribute__((ext_vector_type(8))) short bf16x8;
typedef __attribute__((ext_vector_type(4))) float f32x4;
typedef __attribute__((ext_vector_type(16))) float f32x16;
typedef __attribute__((ext_vector_type(4))) unsigned u32x4;
typedef __attribute__((ext_vector_type(2))) unsigned u32x2;

__device__ inline short f2bf(float f) {
    union { float f; unsigned u; } v; v.f = f;
    unsigned r = v.u + 0x7FFFu + ((v.u >> 16) & 1u);
    return (short)(r >> 16);
}
__device__ inline float bf2f(short s) {
    union { unsigned u; float f; } v; v.u = ((unsigned)(unsigned short)s) << 16;
    return v.f;
}
// native 2^x (v_exp_f32)
__device__ inline float exp2fast(float x) { return __builtin_amdgcn_exp2f(x); }
// packed bf16(lo) | bf16(hi)<<16, RNE
__device__ inline unsigned cvtpk(float lo, float hi) {
    unsigned r;
    asm("v_cvt_pk_bf16_f32 %0, %1, %2" : "=v"(r) : "v"(lo), "v"(hi));
    return r;
}
// permlane32_swap via builtin (hazard-safe: compiler inserts the required
// VALU->permlane wait states; raw inline asm did not - round 10 failure).
__device__ inline u32x2 pswap(unsigned a, unsigned b) {
    return __builtin_amdgcn_permlane32_swap(a, b, false, false);
}
// cross-half (lane^32) max/add, direction-agnostic
__device__ inline float xmax32(float x) {
    u32x2 r = pswap(__float_as_uint(x), __float_as_uint(x));
    return fmaxf(__uint_as_float(r[0]), __uint_as_float(r[1]));
}
__device__ inline float xadd32(float x) {
    u32x2 r = pswap(__float_as_uint(x), __float_as_uint(x));
    return __uint_as_float(r[0]) + __uint_as_float(r[1]);
}

// async global -> LDS, 16 B per lane (wave-uniform LDS base + lane*16)
#define GLL16(gp, lp) __builtin_amdgcn_global_load_lds( \
    (const __attribute__((address_space(1))) unsigned int*)(gp), \
    (__attribute__((address_space(3))) unsigned int*)(lp), 16, 0, 0)

// -------- f32 -> bf16 pre-conversion of x, Wqkv, Wproj (one launch) --------
__global__ __launch_bounds__(256) void cvt_bf16(const float* __restrict__ x,
        const float* __restrict__ w1, const float* __restrict__ w2,
        short* __restrict__ xb, short* __restrict__ w1b, short* __restrict__ w2b) {
    size_t i = ((size_t)blockIdx.x * 256 + threadIdx.x) * 8;
    const float* src; short* dst; size_t off;
    if (i < (size_t)NX)              { src = x;  dst = xb;  off = i; }
    else if (i < (size_t)NX + NW1)   { src = w1; dst = w1b; off = i - NX; }
    else                             { src = w2; dst = w2b; off = i - NX - NW1; }
    f32x4 a = *(const f32x4*)(src + off);
    f32x4 b = *(const f32x4*)(src + off + 4);
    bf16x8 r;
    r[0] = f2bf(a[0]); r[1] = f2bf(a[1]); r[2] = f2bf(a[2]); r[3] = f2bf(a[3]);
    r[4] = f2bf(b[0]); r[5] = f2bf(b[1]); r[6] = f2bf(b[2]); r[7] = f2bf(b[3]);
    *(bf16x8*)(dst + off) = r;
}

// C(M,N) = A(M,K) * B(N,K)^T, bf16 inputs, fp32 accum.
// v10 (round-22, kept) + 3 blocks/CU (LDS 48KB x3 = 144 <= 160 KiB;
// launch_bounds(256,3) caps VGPR at 170, GEMM uses ~100): 128x64 tile,
// BK=64, LDS double-buffer, m201 XOR-swizzle, 4 waves (2x2).
template <bool OUT_BF16>
__global__ __launch_bounds__(256, 3) void gemm_bt(const short* __restrict__ A,
                                                  const short* __restrict__ Bm,
                                                  void* __restrict__ Cv,
                                                  int M, int N, int K) {
    __shared__ short lA[2][128 * 64];   // 32 KB
    __shared__ short lB[2][64 * 64];    // 16 KB
    int ntn = N >> 6;
    int nwg = (M >> 7) * ntn;
    int cpx = nwg >> 3;                         // grids are %8 == 0
    int bid = (int)blockIdx.x;
    int swz = (bid % 8) * cpx + bid / 8;        // bijective XCD swizzle
    int m0 = (swz / ntn) << 7;
    int n0 = (swz % ntn) << 6;
    int t = threadIdx.x;
    int wid = t >> 6, l = t & 63;
    int wr = wid >> 1, wc = wid & 1;
    int c = l & 15, g = l >> 4;

    // staging: A tile 128x64 = 1024 16B-chunks (4/thread); B 64x64 = 512 (2/thread)
    // LDS slot (row, sl) holds global chunk sl ^ (row&7)  (m201 both-sides swizzle)
    const short* gAsrc[4];
    int lAoff[4];
    #pragma unroll
    for (int i = 0; i < 4; i++) {
        int cidx = t + i * 256;
        int row = cidx >> 3, sl = cidx & 7;
        gAsrc[i] = A + (size_t)(m0 + row) * K + ((sl ^ (row & 7)) * 8);
        lAoff[i] = cidx * 8;
    }
    const short* gBsrc[2];
    int lBoff[2];
    #pragma unroll
    for (int i = 0; i < 2; i++) {
        int cidx = t + i * 256;
        int row = cidx >> 3, sl = cidx & 7;
        gBsrc[i] = Bm + (size_t)(n0 + row) * K + ((sl ^ (row & 7)) * 8);
        lBoff[i] = cidx * 8;
    }

    int nstep = K >> 6;                          // 16 for K=1024
    f32x4 acc[4][2] = {};
    int cur = 0;
    #pragma unroll
    for (int i = 0; i < 4; i++) GLL16(gAsrc[i], &lA[0][lAoff[i]]);
    #pragma unroll
    for (int i = 0; i < 2; i++) GLL16(gBsrc[i], &lB[0][lBoff[i]]);
    for (int it = 0; it < nstep; it++) {
        __syncthreads();                        // drains stage into lX[cur]
        if (it + 1 < nstep) {                   // stage next, overlapped
            int k = (it + 1) << 6;
            #pragma unroll
            for (int i = 0; i < 4; i++) GLL16(gAsrc[i] + k, &lA[cur ^ 1][lAoff[i]]);
            #pragma unroll
            for (int i = 0; i < 2; i++) GLL16(gBsrc[i] + k, &lB[cur ^ 1][lBoff[i]]);
        }
        #pragma unroll
        for (int ks = 0; ks < 2; ks++) {
            bf16x8 a[4], b[2];
            #pragma unroll
            for (int i = 0; i < 4; i++) {
                int row = wr * 64 + i * 16 + c;
                a[i] = *(const bf16x8*)&lA[cur][row * 64 + (((ks * 4 + g) ^ (row & 7)) * 8)];
            }
            #pragma unroll
            for (int j = 0; j < 2; j++) {
                int row = wc * 32 + j * 16 + c;
                b[j] = *(const bf16x8*)&lB[cur][row * 64 + (((ks * 4 + g) ^ (row & 7)) * 8)];
            }
            #pragma unroll
            for (int i = 0; i < 4; i++)
                #pragma unroll
                for (int j = 0; j < 2; j++)
                    acc[i][j] = __builtin_amdgcn_mfma_f32_16x16x32_bf16(a[i], b[j], acc[i][j], 0, 0, 0);
        }
        cur ^= 1;
    }

    #pragma unroll
    for (int i = 0; i < 4; i++)
        #pragma unroll
        for (int j = 0; j < 2; j++)
            #pragma unroll
            for (int r = 0; r < 4; r++) {
                int rr = m0 + wr * 64 + i * 16 + g * 4 + r;   // C/D row = (l>>4)*4 + reg
                int cc = n0 + wc * 32 + j * 16 + c;           // C/D col = l&15
                if (OUT_BF16)
                    ((short*)Cv)[(size_t)rr * N + cc] = f2bf(acc[i][j][r]);
                else
                    ((float*)Cv)[(size_t)rr * N + cc] = acc[i][j][r];
            }
}

// Causal depthwise conv1d (K=3) + bias on bf16 qkv, VECTORIZED x8 (G13):
// each thread handles 8 consecutive channels -> bf16x8 loads of rows
// t/t-1/t-2, 24 contiguous f32 weights, 16B Q/K stores, 8x2B V scatter.
// Splits -> Q (B,H,T,64, scaled QSCALE), K (B,T,64), V transposed (B,64,T).
__global__ __launch_bounds__(256) void conv_split(const short* __restrict__ qkv,
        const float* __restrict__ qw, const float* __restrict__ qb,
        const float* __restrict__ kw, const float* __restrict__ kbias,
        const float* __restrict__ vw, const float* __restrict__ vbias,
        short* __restrict__ Qs, short* __restrict__ Kb, short* __restrict__ Vt) {
    int idx = blockIdx.x * 256 + threadIdx.x;   // B*T*144 total
    int c8 = idx % 144;
    int bt = idx / 144;
    int t = bt % T_;
    int b = bt / T_;
    int ch0 = c8 * 8;
    const short* p = qkv + (size_t)bt * O_ + ch0;
    bf16x8 zv = {};
    bf16x8 x2 = *(const bf16x8*)p;
    bf16x8 x1 = (t >= 1) ? *(const bf16x8*)(p - O_) : zv;
    bf16x8 x0 = (t >= 2) ? *(const bf16x8*)(p - 2 * O_) : zv;

    const float* wb; const float* bb; int cc;
    if (c8 < 128)      { wb = qw; bb = qb;    cc = ch0; }
    else if (c8 < 136) { wb = kw; bb = kbias; cc = ch0 - C_; }
    else               { wb = vw; bb = vbias; cc = ch0 - C_ - HD_; }
    float w[24], bias[8];
    #pragma unroll
    for (int i = 0; i < 6; i++) {
        f32x4 v = *(const f32x4*)(wb + cc * 3 + i * 4);
        w[i * 4] = v[0]; w[i * 4 + 1] = v[1]; w[i * 4 + 2] = v[2]; w[i * 4 + 3] = v[3];
    }
    #pragma unroll
    for (int i = 0; i < 2; i++) {
        f32x4 v = *(const f32x4*)(bb + cc + i * 4);
        bias[i * 4] = v[0]; bias[i * 4 + 1] = v[1]; bias[i * 4 + 2] = v[2]; bias[i * 4 + 3] = v[3];
    }
    float y[8];
    #pragma unroll
    for (int j = 0; j < 8; j++)
        y[j] = fmaf(bf2f(x0[j]), w[j * 3],
               fmaf(bf2f(x1[j]), w[j * 3 + 1],
               fmaf(bf2f(x2[j]), w[j * 3 + 2], bias[j])));

    if (c8 < 128) {
        int h = ch0 >> 6, d = ch0 & 63;
        bf16x8 r;
        #pragma unroll
        for (int j = 0; j < 8; j++) r[j] = f2bf(y[j] * QSCALE);
        *(bf16x8*)&Qs[(((size_t)b * H_ + h) * T_ + t) * HD_ + d] = r;
    } else if (c8 < 136) {
        bf16x8 r;
        #pragma unroll
        for (int j = 0; j < 8; j++) r[j] = f2bf(y[j]);
        *(bf16x8*)&Kb[((size_t)b * T_ + t) * HD_ + cc] = r;
    } else {
        #pragma unroll
        for (int j = 0; j < 8; j++)
            Vt[((size_t)b * HD_ + cc + j) * T_ + t] = f2bf(y[j]);
    }
}

// Flash-style causal MQA, v14 (round-20, kept): LDS-shared K/V across 4 heads,
// 128-row barrier rounds, double-buffered, XOR-swizzled staging/reads,
// swapped QK^T + exp2 softmax + tree reductions + T12/T13.
// C/D layout (m74-verified): col=lane&31, row=(reg&3)+8*(reg>>2)+4*(lane>>5).
__global__ __launch_bounds__(256, 2) void attn_kernel(const short* __restrict__ Qs,
        const short* __restrict__ Kb, const short* __restrict__ Vt,
        short* __restrict__ Y) {
    __shared__ short KL[2][2][64 * 64];   // 32 KB (2 bufs x 2 subtiles x 8 KB)
    __shared__ short VL[2][2][64 * 64];   // 32 KB
    int n = (int)blockIdx.x;                   // 0..511
    int half = n >> 8;
    int n2 = n & 255;
    int y = n2 >> 5;                           // 0..7: b*4 + hq
    int qx = n2 & 31;
    int qt = half ? qx : 63 - qx;              // heavy first
    int b = y >> 2;
    int hq = y & 3;
    int t = threadIdx.x;
    int wid = t >> 6, l = t & 63;
    int ql = l & 31, hi = l >> 5;
    int h = hq * 4 + wid;
    int bh = b * H_ + h;
    int qbase = qt * 32;
    int qi = qbase + ql;

    // Q B-fragments (col=q=ql, d=hi*8+j), per-wave head
    const short* Qp = Qs + ((size_t)bh * T_ + qi) * HD_ + hi * 8;
    bf16x8 qf[4];
    #pragma unroll
    for (int s = 0; s < 4; s++) qf[s] = *(const bf16x8*)(Qp + s * 16);

    f32x16 Oa0 = {}, Oa1 = {};                 // O^T, d-blocks [0,32) and [32,64)
    float mrow = -1e30f, lsum = 0.f;

    const short* Kbase = Kb + (size_t)b * T_ * HD_;
    const short* Vbase = Vt + (size_t)b * HD_ * T_;

    // ---- staging geometry: thread t -> row krow = t>>3, col16 = t&7 ----
    // LDS linear slot (row, s16) holds global col16 = s16 ^ (row&7)  (m201).
    int krow = t >> 3;
    int sc = ((t & 7) ^ (krow & 7)) * 8;       // pre-swizzled source col (elems)
    const short* KgA = Kbase + (size_t)krow * HD_ + sc;   // + kt0*HD at stage
    const short* VgA = Vbase + (size_t)krow * T_ + sc;    // + kt0 at stage
    int t8 = t * 8;                             // LDS short index (t*16 bytes)

    auto STAGE1 = [&](short* Kd, short* Vd, int kt0) {
        GLL16(KgA + (size_t)kt0 * HD_, Kd + t8);
        GLL16(KgA + (size_t)(kt0 + 32) * HD_, Kd + 2048 + t8);
        GLL16(VgA + kt0, Vd + t8);
        GLL16(VgA + kt0 + (size_t)32 * T_, Vd + 2048 + t8);
    };

    // process one 64-row subtile from LDS
    auto PROC = [&](const short* Kt, const short* Vtl, int kt0) {
        // ---- S^T from swizzled LDS K ----
        f32x16 sv0 = {}, sv1 = {};
        #pragma unroll
        for (int s = 0; s < 4; s++) {
            bf16x8 ka = *(const bf16x8*)&Kt[ql * 64 + (((s * 2 + hi) ^ (ql & 7)) * 8)];
            sv0 = __builtin_amdgcn_mfma_f32_32x32x16_bf16(ka, qf[s], sv0, 0, 0, 0);
        }
        #pragma unroll
        for (int s = 0; s < 4; s++) {
            bf16x8 ka = *(const bf16x8*)&Kt[(32 + ql) * 64 + (((s * 2 + hi) ^ (ql & 7)) * 8)];
            sv1 = __builtin_amdgcn_mfma_f32_32x32x16_bf16(ka, qf[s], sv1, 0, 0, 0);
        }
        // ---- causal mask (diagonal tile only; scale folded into Q) ----
        if (kt0 + 64 > qbase) {
            #pragma unroll
            for (int r = 0; r < 16; r++) {
                int kl = (r & 3) + 8 * (r >> 2) + 4 * hi;
                if (kt0 + kl > qi)      sv0[r] = -1e30f;
                if (kt0 + 32 + kl > qi) sv1[r] = -1e30f;
            }
        }
        // ---- row max: depth-5 tree + cross-half combine ----
        float t8v[8];
        #pragma unroll
        for (int r = 0; r < 8; r++)
            t8v[r] = fmaxf(fmaxf(sv0[r], sv0[r + 8]), fmaxf(sv1[r], sv1[r + 8]));
        float pmax = fmaxf(fmaxf(fmaxf(t8v[0], t8v[4]), fmaxf(t8v[1], t8v[5])),
                           fmaxf(fmaxf(t8v[2], t8v[6]), fmaxf(t8v[3], t8v[7])));
        pmax = xmax32(pmax);
        // ---- defer-max (T13): rescale only when max grew past THR=8 ----
        if (!__all(pmax <= mrow + 8.f)) {
            float nm = fmaxf(mrow, pmax);
            float alpha = exp2fast(mrow - nm);
            mrow = nm;
            lsum *= alpha;
            #pragma unroll
            for (int r = 0; r < 16; r++) { Oa0[r] *= alpha; Oa1[r] *= alpha; }
        }
        // ---- P = exp2(S - m); sum via depth-5 tree + cross-half add ----
        #pragma unroll
        for (int r = 0; r < 16; r++) sv0[r] = exp2fast(sv0[r] - mrow);
        #pragma unroll
        for (int r = 0; r < 16; r++) sv1[r] = exp2fast(sv1[r] - mrow);
        float s8[8];
        #pragma unroll
        for (int r = 0; r < 8; r++)
            s8[r] = (sv0[r] + sv0[r + 8]) + (sv1[r] + sv1[r + 8]);
        float psum = ((s8[0] + s8[4]) + (s8[1] + s8[5])) +
                     ((s8[2] + s8[6]) + (s8[3] + s8[7]));
        lsum += xadd32(psum);
        // ---- P redistribution (cvt_pk + permlane32_swap) + PV from LDS V ----
        #pragma unroll
        for (int sub = 0; sub < 2; sub++) {
            #pragma unroll
            for (int hh = 0; hh < 2; hh++) {
                unsigned X0, X1, X2, X3;
                if (sub == 0) {
                    X0 = cvtpk(sv0[hh * 8 + 0], sv0[hh * 8 + 1]);
                    X1 = cvtpk(sv0[hh * 8 + 2], sv0[hh * 8 + 3]);
                    X2 = cvtpk(sv0[hh * 8 + 4], sv0[hh * 8 + 5]);
                    X3 = cvtpk(sv0[hh * 8 + 6], sv0[hh * 8 + 7]);
                } else {
                    X0 = cvtpk(sv1[hh * 8 + 0], sv1[hh * 8 + 1]);
                    X1 = cvtpk(sv1[hh * 8 + 2], sv1[hh * 8 + 3]);
                    X2 = cvtpk(sv1[hh * 8 + 4], sv1[hh * 8 + 5]);
                    X3 = cvtpk(sv1[hh * 8 + 6], sv1[hh * 8 + 7]);
                }
                u32x2 r02 = pswap(X0, X2);
                u32x2 r13 = pswap(X1, X3);
                union { u32x4 u; bf16x8 v; } pw;
                pw.u[0] = r02[0];   // k elems (hi*8 + 0,1)
                pw.u[1] = r13[0];   // k elems (hi*8 + 2,3)
                pw.u[2] = r02[1];   // k elems (hi*8 + 4,5)
                pw.u[3] = r13[1];   // k elems (hi*8 + 6,7)
                int u = sub * 2 + hh;           // V col16 = u*2 + hi
                bf16x8 va0 = *(const bf16x8*)&Vtl[ql * 64 + (((u * 2 + hi) ^ (ql & 7)) * 8)];
                bf16x8 va1 = *(const bf16x8*)&Vtl[(32 + ql) * 64 + (((u * 2 + hi) ^ (ql & 7)) * 8)];
                Oa0 = __builtin_amdgcn_mfma_f32_32x32x16_bf16(va0, pw.v, Oa0, 0, 0, 0);
                Oa1 = __builtin_amdgcn_mfma_f32_32x32x16_bf16(va1, pw.v, Oa1, 0, 0, 0);
            }
        }
    };

    int nt = (qt >> 1) + 1;                    // 64-row tiles
    int nr = (nt + 1) >> 1;                    // 128-row rounds
    int cur = 0;
    STAGE1(KL[0][0], VL[0][0], 0);
    STAGE1(KL[0][1], VL[0][1], 64);
    for (int r = 0; r < nr; r++) {
        __syncthreads();                        // buf[cur] ready (vmcnt drained)
        if (r + 1 < nr) {
            int base = (r + 1) * 128;
            STAGE1(KL[cur ^ 1][0], VL[cur ^ 1][0], base);
            STAGE1(KL[cur ^ 1][1], VL[cur ^ 1][1], base + 64);
        }
        PROC(KL[cur][0], VL[cur][0], r * 128);
        if (r * 2 + 1 < nt)
            PROC(KL[cur][1], VL[cur][1], r * 128 + 64);
        cur ^= 1;
    }
    // ---- epilogue: normalize, write one Y-row segment per lane ----
    float inv = 1.f / lsum;
    size_t orow = ((size_t)b * T_ + qi) * C_ + h * HD_;
    #pragma unroll
    for (int r = 0; r < 16; r += 2) {
        int d = (r & 3) + 8 * (r >> 2) + 4 * hi;       // (r,r+1)->(d,d+1)
        *(unsigned*)(Y + orow + d)      = cvtpk(Oa0[r] * inv, Oa0[r + 1] * inv);
        *(unsigned*)(Y + orow + 32 + d) = cvtpk(Oa1[r] * inv, Oa1[r + 1] * inv);
    }
}

extern "C" void kernel_launch(void* const* d_in, const int* in_sizes, int n_in,
                              void* d_out, int out_size, void* d_ws, size_t ws_size,
                              hipStream_t stream) {
    const float* x     = (const float*)d_in[0];
    const float* Wqkv  = (const float*)d_in[1];
    const float* qw    = (const float*)d_in[2];
    const float* qb    = (const float*)d_in[3];
    const float* kw    = (const float*)d_in[4];
    const float* kbias = (const float*)d_in[5];
    const float* vw    = (const float*)d_in[6];
    const float* vbias = (const float*)d_in[7];
    const float* Wproj = (const float*)d_in[8];

    char* ws = (char*)d_ws;
    short* xb     = (short*)ws;                    //  8388608 B (reused as Ybf later)
    short* Wqkvb  = (short*)(ws + 8388608);        //  2359296 B
    short* Wprojb = (short*)(ws + 10747904);       //  2097152 B
    short* qkvb   = (short*)(ws + 12845056);       //  9437184 B
    short* Qsc    = (short*)(ws + 22282240);       //  8388608 B
    short* Kbf    = (short*)(ws + 30670848);       //   524288 B
    short* Vtr    = (short*)(ws + 31195136);       //   524288 B  (total 31.7 MB)
    short* Ybf    = xb;                            // x dead after gemm1

    const int M = B_ * T_;  // 4096

    // 0) f32 -> bf16: x, Wqkv, Wproj
    cvt_bf16<<<dim3(3136), 256, 0, stream>>>(x, Wqkv, Wproj, xb, Wqkvb, Wprojb);

    // 1) qkv = x @ Wqkv^T  (bf16 out)   grid 32*18 = 576 (%8==0)
    gemm_bt<true><<<dim3((M / 128) * (O_ / 64)), 256, 0, stream>>>(
        xb, Wqkvb, qkvb, M, O_, C_);

    // 2) causal dwconv + split + scale + V-transpose (x8 vectorized)
    conv_split<<<dim3((B_ * T_ * 144) / 256), 256, 0, stream>>>(
        qkvb, qw, qb, kw, kbias, vw, vbias, Qsc, Kbf, Vtr);

    // 3) causal MQA attention -> y (B,T,C) bf16   (LDS-shared K/V, 128-row rounds)
    attn_kernel<<<dim3(512), 256, 0, stream>>>(Qsc, Kbf, Vtr, Ybf);

    // 4) out = y @ Wproj^T -> f32 d_out   grid 32*16 = 512 (%8==0)
    gemm_bt<false><<<dim3((M / 128) * (C_ / 64)), 256, 0, stream>>>(
        Ybf, Wprojb, (float*)d_out, M, C_, C_);
}